// Round 1
// baseline (2573.741 us; speedup 1.0000x reference)
//
#include <hip/hip_runtime.h>

#define N_NODES 10000
#define N_EDGES 40000
#define HD 64
#define MAXD 12
#define CAP 32

__device__ __forceinline__ float sigmoidf_(float x) {
  return 1.0f / (1.0f + __expf(-x));
}
__device__ __forceinline__ float tanhf_(float x) {
  float ax = fabsf(x);
  float t = __expf(-2.0f * ax);
  float r = (1.0f - t) / (1.0f + t);
  return copysignf(r, x);
}

// ---------------- adjacency build ----------------

__global__ void scatter_kernel(const int* __restrict__ edges, int* __restrict__ cnt,
                               int* __restrict__ pool) {
  int idx = blockIdx.x * 256 + threadIdx.x;
  if (idx >= 4 * N_EDGES) return;
  int et = idx / N_EDGES, e = idx - et * N_EDGES;
  int src = edges[(et * 2) * N_EDGES + e];
  int dst = edges[(et * 2 + 1) * N_EDGES + e];
  int slot = atomicAdd(&cnt[et * N_NODES + dst], 1);
  if (slot < CAP) pool[(et * N_NODES + dst) * CAP + slot] = src;
}

__global__ void sortrows_kernel(const int* __restrict__ cnt, const int* __restrict__ pool,
                                int* __restrict__ nbr) {
  __shared__ int buf[64][CAP + 1];
  int idx = blockIdx.x * 64 + threadIdx.x;
  if (idx >= 4 * N_NODES) return;
  int n = idx % N_NODES;
  int c = cnt[idx];
  if (c > CAP) c = CAP;
  int* a = buf[threadIdx.x];
  const int* row = pool + idx * CAP;
  for (int j = 0; j < c; ++j) a[j] = row[j] * 2;
  a[c] = n * 2 + 1;  // self loop sorts after equal-src originals (stable argsort semantics)
  ++c;
  for (int i2 = 1; i2 < c; ++i2) {
    int key = a[i2];
    int b = i2 - 1;
    while (b >= 0 && a[b] > key) { a[b + 1] = a[b]; --b; }
    a[b + 1] = key;
  }
  int* onbr = nbr + idx * MAXD;
  for (int t = 0; t < MAXD; ++t) onbr[t] = (t < c) ? (a[t] >> 1) : -1;
}

// ---------------- node encoders ----------------

template <int IN>
__global__ __launch_bounds__(256) void encode_kernel(const float* __restrict__ x,
    const float* __restrict__ W1, const float* __restrict__ b1,
    const float* __restrict__ W2, const float* __restrict__ b2, float* __restrict__ out) {
  __shared__ float xs[4][IN];
  __shared__ float h1[4][HD];
  int w = threadIdx.x >> 6, l = threadIdx.x & 63;
  int n = blockIdx.x * 4 + w;
  if (l < IN) xs[w][l] = x[n * IN + l];
  __syncthreads();
  float acc = b1[l];
#pragma unroll
  for (int k = 0; k < IN; ++k) acc = fmaf(xs[w][k], W1[l * IN + k], acc);
  h1[w][l] = fmaxf(acc, 0.0f);
  __syncthreads();
  float acc2 = b2[l];
#pragma unroll
  for (int k = 0; k < HD; ++k) acc2 = fmaf(h1[w][k], W2[l * HD + k], acc2);
  out[n * HD + l] = acc2;
}

// ---------------- y = x_src @ Wih.T ----------------

__global__ __launch_bounds__(256) void ygemm_kernel(const float* __restrict__ x,
    const float* __restrict__ Wih, float* __restrict__ y) {
  __shared__ __align__(16) float xs[16][HD];
  int w = threadIdx.x >> 6, l = threadIdx.x & 63;
  int n0 = blockIdx.x * 16;
  for (int r = threadIdx.x; r < 16 * HD; r += 256) xs[r >> 6][r & 63] = x[n0 * HD + r];
  __syncthreads();
  int j = w * 64 + l;
  float4 wr[16];
  const float4* W4 = (const float4*)(Wih + j * HD);
#pragma unroll
  for (int kk = 0; kk < 16; ++kk) wr[kk] = W4[kk];
  for (int m = 0; m < 16; ++m) {
    float acc = 0.0f;
    const float4* xv4 = (const float4*)xs[m];
    float acc2 = 0.0f;
#pragma unroll
    for (int kk = 0; kk < 16; kk += 2) {
      float4 xv = xv4[kk], wv = wr[kk];
      acc = fmaf(wv.x, xv.x, acc); acc = fmaf(wv.y, xv.y, acc);
      acc = fmaf(wv.z, xv.z, acc); acc = fmaf(wv.w, xv.w, acc);
      float4 xv2 = xv4[kk + 1], wv2 = wr[kk + 1];
      acc2 = fmaf(wv2.x, xv2.x, acc2); acc2 = fmaf(wv2.y, xv2.y, acc2);
      acc2 = fmaf(wv2.z, xv2.z, acc2); acc2 = fmaf(wv2.w, xv2.w, acc2);
    }
    y[(n0 + m) * 256 + j] = acc + acc2;
  }
}

// ---------------- SAGE-LSTM aggregation ----------------
// 256 threads = 4 waves = 4 nodes. Wave w holds Whh rows [64w,64w+64) in regs,
// computes gate group w (i,f,g,o torch order) for all 4 nodes. Thread (w,l)
// owns (node w, unit l) for the c/h update.

__global__ __launch_bounds__(256) void lstm_kernel(const int* __restrict__ nbr,
    const float* __restrict__ y, const float* __restrict__ Whh,
    const float* __restrict__ bih, const float* __restrict__ bhh, float* __restrict__ agg) {
  __shared__ __align__(16) float hS[4][HD];
  __shared__ __align__(16) float gS[4][4][HD];  // [gate][node][unit]
  __shared__ int nbS[4][MAXD];
  int w = threadIdx.x >> 6, l = threadIdx.x & 63;
  int n0 = blockIdx.x * 4;
  int j = w * 64 + l;
  float4 wr[16];
  const float4* W4 = (const float4*)(Whh + j * HD);
#pragma unroll
  for (int kk = 0; kk < 16; ++kk) wr[kk] = W4[kk];
  float bsum = bih[j] + bhh[j];
  if (threadIdx.x < 4 * MAXD)
    nbS[threadIdx.x / MAXD][threadIdx.x % MAXD] = nbr[n0 * MAXD + threadIdx.x];
  hS[w][l] = 0.0f;
  float c = 0.0f, h = 0.0f;
  __syncthreads();
  float yv[4];
#pragma unroll
  for (int m = 0; m < 4; ++m) {
    int nb = nbS[m][0];
    yv[m] = (nb >= 0) ? y[nb * 256 + j] : 0.0f;
  }
  for (int t = 0; t < MAXD; ++t) {
    float acc[4];
#pragma unroll
    for (int m = 0; m < 4; ++m) acc[m] = bsum + yv[m];
    if (t + 1 < MAXD) {
#pragma unroll
      for (int m = 0; m < 4; ++m) {
        int nb = nbS[m][t + 1];
        yv[m] = (nb >= 0) ? y[nb * 256 + j] : 0.0f;
      }
    }
#pragma unroll
    for (int kk = 0; kk < 16; ++kk) {
      float4 wv = wr[kk];
#pragma unroll
      for (int m = 0; m < 4; ++m) {
        float4 hv = ((const float4*)hS[m])[kk];
        acc[m] = fmaf(wv.x, hv.x, acc[m]);
        acc[m] = fmaf(wv.y, hv.y, acc[m]);
        acc[m] = fmaf(wv.z, hv.z, acc[m]);
        acc[m] = fmaf(wv.w, hv.w, acc[m]);
      }
    }
#pragma unroll
    for (int m = 0; m < 4; ++m) gS[w][m][l] = acc[m];
    __syncthreads();  // gates ready; all hS reads of this step done
    float gi = gS[0][w][l], gf = gS[1][w][l], gg = gS[2][w][l], go = gS[3][w][l];
    float i_ = sigmoidf_(gi), f_ = sigmoidf_(gf);
    float g_ = tanhf_(gg), o_ = sigmoidf_(go);
    c = fmaf(f_, c, i_ * g_);
    h = o_ * tanhf_(c);
    hS[w][l] = h;
    __syncthreads();  // new h visible before next step's matmul
  }
  agg[(n0 + w) * HD + l] = h;
}

// ---------------- hetero mean + SAGE linear + residual + relu ----------------

__global__ __launch_bounds__(256) void combine_kernel(
    const float* __restrict__ aggA, const float* __restrict__ aggB,
    const float* __restrict__ WlA, const float* __restrict__ blA, const float* __restrict__ WrA,
    const float* __restrict__ WlB, const float* __restrict__ blB, const float* __restrict__ WrB,
    const float* __restrict__ xin, int has_res, float* __restrict__ out) {
  __shared__ __align__(16) float aS[4][HD], bS[4][HD], xS[4][HD];
  int w = threadIdx.x >> 6, l = threadIdx.x & 63;
  int n = blockIdx.x * 4 + w;
  aS[w][l] = aggA[n * HD + l];
  bS[w][l] = aggB[n * HD + l];
  xS[w][l] = xin[n * HD + l];
  __syncthreads();
  float acc = blA[l] + blB[l];
  const float4* wla = (const float4*)(WlA + l * HD);
  const float4* wlb = (const float4*)(WlB + l * HD);
  const float4* wra = (const float4*)(WrA + l * HD);
  const float4* wrb = (const float4*)(WrB + l * HD);
  const float4* av4 = (const float4*)aS[w];
  const float4* bv4 = (const float4*)bS[w];
  const float4* xv4 = (const float4*)xS[w];
#pragma unroll
  for (int kk = 0; kk < 16; ++kk) {
    float4 wa = wla[kk], wb = wlb[kk], ra = wra[kk], rb = wrb[kk];
    float4 av = av4[kk], bv = bv4[kk], xv = xv4[kk];
    acc = fmaf(wa.x, av.x, acc); acc = fmaf(wa.y, av.y, acc);
    acc = fmaf(wa.z, av.z, acc); acc = fmaf(wa.w, av.w, acc);
    acc = fmaf(wb.x, bv.x, acc); acc = fmaf(wb.y, bv.y, acc);
    acc = fmaf(wb.z, bv.z, acc); acc = fmaf(wb.w, bv.w, acc);
    acc = fmaf(ra.x + rb.x, xv.x, acc); acc = fmaf(ra.y + rb.y, xv.y, acc);
    acc = fmaf(ra.z + rb.z, xv.z, acc); acc = fmaf(ra.w + rb.w, xv.w, acc);
  }
  float v = 0.5f * acc + (has_res ? xS[w][l] : 0.0f);
  out[n * HD + l] = fmaxf(v, 0.0f);
}

// ---------------- edge head ----------------
// one wave per edge (grid-stride); MLP weights transposed in LDS; x broadcast by shuffle.

__global__ __launch_bounds__(256) void edge_head_kernel(
    const int* __restrict__ esrc, const int* __restrict__ edst, const float* __restrict__ ea,
    const float* __restrict__ s3, const float* __restrict__ t3,
    const float* __restrict__ Wg1, const float* __restrict__ bg1,
    const float* __restrict__ Wg2, const float* __restrict__ bg2,
    const float* __restrict__ Wm1, const float* __restrict__ bm1,
    const float* __restrict__ Wm2, const float* __restrict__ bm2,
    const float* __restrict__ Wm3, const float* __restrict__ bm3, float* __restrict__ out) {
  __shared__ float g1T[128 * 64];
  __shared__ float m1T[80 * 64];
  __shared__ float m2T[64 * 32];
  int tid = threadIdx.x;
  for (int idx = tid; idx < 128 * 64; idx += 256) {
    int jj = idx >> 7, k = idx & 127;
    g1T[k * 64 + jj] = Wg1[idx];
  }
  for (int idx = tid; idx < 80 * 64; idx += 256) {
    int jj = idx / 80, k = idx - jj * 80;
    m1T[k * 64 + jj] = Wm1[idx];
  }
  for (int idx = tid; idx < 64 * 32; idx += 256) {
    int jj = idx >> 6, k = idx & 63;
    m2T[k * 32 + jj] = Wm2[idx];
  }
  __syncthreads();
  int w = tid >> 6, l = tid & 63;
  int wave = blockIdx.x * 4 + w;
  int nw = gridDim.x * 4;
  float wg2l = Wg2[l], bg1l = bg1[l], bg2v = bg2[0], bm1l = bm1[l], bm2l = bm2[l & 31];
  float wm3a = Wm3[l & 31], wm3b = Wm3[32 + (l & 31)];
  float bm3a = bm3[0], bm3b = bm3[1];
  for (int e = wave; e < N_EDGES; e += nw) {
    int s = esrc[e], d = edst[e];
    float se = s3[s * 64 + l];
    float te = t3[d * 64 + l];
    float acc = bg1l;
#pragma unroll
    for (int k = 0; k < 64; ++k) acc = fmaf(__shfl(se, k), g1T[k * 64 + l], acc);
#pragma unroll
    for (int k = 0; k < 64; ++k) acc = fmaf(__shfl(te, k), g1T[(64 + k) * 64 + l], acc);
    float h1 = fmaxf(acc, 0.0f);
    float p = h1 * wg2l;
#pragma unroll
    for (int off = 32; off; off >>= 1) p += __shfl_xor(p, off);
    float g = sigmoidf_(p + bg2v);
    float er = fmaf(g, se - te, te);  // g*se + (1-g)*te
    float eav = (l < 16) ? ea[e * 16 + l] : 0.0f;
    float acc2 = bm1l;
#pragma unroll
    for (int k = 0; k < 64; ++k) acc2 = fmaf(__shfl(er, k), m1T[k * 64 + l], acc2);
#pragma unroll
    for (int k = 0; k < 16; ++k) acc2 = fmaf(__shfl(eav, k), m1T[(64 + k) * 64 + l], acc2);
    float h2 = fmaxf(acc2, 0.0f);
    float acc3 = bm2l;
#pragma unroll
    for (int k = 0; k < 64; ++k) acc3 = fmaf(__shfl(h2, k), m2T[k * 32 + (l & 31)], acc3);
    float h3 = (l < 32) ? fmaxf(acc3, 0.0f) : 0.0f;
    float p0 = h3 * wm3a;
    float p1 = h3 * wm3b;
#pragma unroll
    for (int off = 32; off; off >>= 1) {
      p0 += __shfl_xor(p0, off);
      p1 += __shfl_xor(p1, off);
    }
    if (l == 0) {
      out[e * 2 + 0] = p0 + bm3a;
      out[e * 2 + 1] = p1 + bm3b;
    }
  }
}

// ---------------- host orchestration ----------------

extern "C" void kernel_launch(void* const* d_in, const int* in_sizes, int n_in, void* d_out,
                              int out_size, void* d_ws, size_t ws_size, hipStream_t stream) {
  const float* x_source = (const float*)d_in[0];
  const float* x_target = (const float*)d_in[1];
  const int* edges = (const int*)d_in[2];
  const float* edge_attr = (const float*)d_in[3];
  const float* We_s1 = (const float*)d_in[4];
  const float* be_s1 = (const float*)d_in[5];
  const float* We_s2 = (const float*)d_in[6];
  const float* be_s2 = (const float*)d_in[7];
  const float* We_t1 = (const float*)d_in[8];
  const float* be_t1 = (const float*)d_in[9];
  const float* We_t2 = (const float*)d_in[10];
  const float* be_t2 = (const float*)d_in[11];
  const float* Wih = (const float*)d_in[12];
  const float* Whh = (const float*)d_in[13];
  const float* bih = (const float*)d_in[14];
  const float* bhh = (const float*)d_in[15];
  const float* Wl = (const float*)d_in[16];
  const float* bl = (const float*)d_in[17];
  const float* Wr = (const float*)d_in[18];
  const float* Wg1 = (const float*)d_in[19];
  const float* bg1 = (const float*)d_in[20];
  const float* Wg2 = (const float*)d_in[21];
  const float* bg2 = (const float*)d_in[22];
  const float* Wm1 = (const float*)d_in[23];
  const float* bm1 = (const float*)d_in[24];
  const float* Wm2 = (const float*)d_in[25];
  const float* bm2 = (const float*)d_in[26];
  const float* Wm3 = (const float*)d_in[27];
  const float* bm3 = (const float*)d_in[28];
  float* out = (float*)d_out;

  // workspace carve (≈38 MB)
  int* nbr = (int*)d_ws;                       // 4*N*12
  int* cnt = nbr + 4 * N_NODES * MAXD;         // 4*N
  int* pool = cnt + 4 * N_NODES;               // 4*N*CAP
  float* fb = (float*)(pool + 4 * N_NODES * CAP);
  float* bufS[2] = {fb, fb + N_NODES * HD};
  float* bufT[2] = {fb + 2 * N_NODES * HD, fb + 3 * N_NODES * HD};
  float* agg[4];
  for (int i = 0; i < 4; ++i) agg[i] = fb + (size_t)(4 + i) * N_NODES * HD;
  float* y = fb + (size_t)8 * N_NODES * HD;    // N*256

  hipMemsetAsync(cnt, 0, 4 * N_NODES * sizeof(int), stream);
  scatter_kernel<<<(4 * N_EDGES + 255) / 256, 256, 0, stream>>>(edges, cnt, pool);
  sortrows_kernel<<<(4 * N_NODES + 63) / 64, 64, 0, stream>>>(cnt, pool, nbr);
  encode_kernel<32><<<N_NODES / 4, 256, 0, stream>>>(x_source, We_s1, be_s1, We_s2, be_s2, bufS[0]);
  encode_kernel<24><<<N_NODES / 4, 256, 0, stream>>>(x_target, We_t1, be_t1, We_t2, be_t2, bufT[0]);

  int cs = 0, ct = 0;
  for (int L = 0; L < 3; ++L) {
    for (int et = 0; et < 4; ++et) {
      int i = L * 4 + et;
      const float* xsrc = (et == 0 || et == 2) ? bufS[cs] : bufT[ct];
      ygemm_kernel<<<N_NODES / 16, 256, 0, stream>>>(xsrc, Wih + (size_t)i * 256 * 64, y);
      lstm_kernel<<<N_NODES / 4, 256, 0, stream>>>(nbr + et * N_NODES * MAXD, y,
          Whh + (size_t)i * 256 * 64, bih + i * 256, bhh + i * 256, agg[et]);
    }
    int i0 = L * 4 + 0, i1 = L * 4 + 1, i2 = L * 4 + 2, i3 = L * 4 + 3;
    // source nodes receive from et0 (src->src) and et3 (tgt->src)
    combine_kernel<<<N_NODES / 4, 256, 0, stream>>>(agg[0], agg[3],
        Wl + i0 * 4096, bl + i0 * 64, Wr + i0 * 4096,
        Wl + i3 * 4096, bl + i3 * 64, Wr + i3 * 4096,
        bufS[cs], L > 0 ? 1 : 0, bufS[1 - cs]);
    // target nodes receive from et1 (tgt->tgt) and et2 (src->tgt)
    combine_kernel<<<N_NODES / 4, 256, 0, stream>>>(agg[1], agg[2],
        Wl + i1 * 4096, bl + i1 * 64, Wr + i1 * 4096,
        Wl + i2 * 4096, bl + i2 * 64, Wr + i2 * 4096,
        bufT[ct], L > 0 ? 1 : 0, bufT[1 - ct]);
    cs = 1 - cs;
    ct = 1 - ct;
  }

  edge_head_kernel<<<512, 256, 0, stream>>>(edges + 4 * N_EDGES, edges + 5 * N_EDGES, edge_attr,
      bufS[cs], bufT[ct], Wg1, bg1, Wg2, bg2, Wm1, bm1, Wm2, bm2, Wm3, bm3, out);
}

// Round 2
// 1913.698 us; speedup vs baseline: 1.3449x; 1.3449x over previous
//
#include <hip/hip_runtime.h>

#define N_NODES 10000
#define N_EDGES 40000
#define HD 64
#define MAXD 12
#define CAP 32

__device__ __forceinline__ float sigmoidf_(float x) {
  return 1.0f / (1.0f + __expf(-x));
}
__device__ __forceinline__ float tanhf_(float x) {
  float ax = fabsf(x);
  float t = __expf(-2.0f * ax);
  float r = (1.0f - t) / (1.0f + t);
  return copysignf(r, x);
}
__device__ __forceinline__ float fma4(float4 w, float4 x, float a) {
  a = fmaf(w.x, x.x, a);
  a = fmaf(w.y, x.y, a);
  a = fmaf(w.z, x.z, a);
  return fmaf(w.w, x.w, a);
}

// ---------------- adjacency build ----------------

__global__ void scatter_kernel(const int* __restrict__ edges, int* __restrict__ cnt,
                               int* __restrict__ pool) {
  int idx = blockIdx.x * 256 + threadIdx.x;
  if (idx >= 4 * N_EDGES) return;
  int et = idx / N_EDGES, e = idx - et * N_EDGES;
  int src = edges[(et * 2) * N_EDGES + e];
  int dst = edges[(et * 2 + 1) * N_EDGES + e];
  int slot = atomicAdd(&cnt[et * N_NODES + dst], 1);
  if (slot < CAP) pool[(et * N_NODES + dst) * CAP + slot] = src;
}

__global__ void sortrows_kernel(const int* __restrict__ cnt, const int* __restrict__ pool,
                                int* __restrict__ nbr) {
  __shared__ int buf[64][CAP + 1];
  int idx = blockIdx.x * 64 + threadIdx.x;
  if (idx >= 4 * N_NODES) return;
  int n = idx % N_NODES;
  int c = cnt[idx];
  if (c > CAP) c = CAP;
  int* a = buf[threadIdx.x];
  const int* row = pool + idx * CAP;
  for (int j = 0; j < c; ++j) a[j] = row[j] * 2;
  a[c] = n * 2 + 1;  // self loop sorts after equal-src originals (stable argsort semantics)
  ++c;
  for (int i2 = 1; i2 < c; ++i2) {
    int key = a[i2];
    int b = i2 - 1;
    while (b >= 0 && a[b] > key) { a[b + 1] = a[b]; --b; }
    a[b + 1] = key;
  }
  int* onbr = nbr + idx * MAXD;
  for (int t = 0; t < MAXD; ++t) onbr[t] = (t < c) ? (a[t] >> 1) : -1;
}

// ---------------- node encoders ----------------

template <int IN>
__global__ __launch_bounds__(256) void encode_kernel(const float* __restrict__ x,
    const float* __restrict__ W1, const float* __restrict__ b1,
    const float* __restrict__ W2, const float* __restrict__ b2, float* __restrict__ out) {
  __shared__ float xs[4][IN];
  __shared__ float h1[4][HD];
  int w = threadIdx.x >> 6, l = threadIdx.x & 63;
  int n = blockIdx.x * 4 + w;
  if (l < IN) xs[w][l] = x[n * IN + l];
  __syncthreads();
  float acc = b1[l];
#pragma unroll
  for (int k = 0; k < IN; ++k) acc = fmaf(xs[w][k], W1[l * IN + k], acc);
  h1[w][l] = fmaxf(acc, 0.0f);
  __syncthreads();
  float acc2 = b2[l];
#pragma unroll
  for (int k = 0; k < HD; ++k) acc2 = fmaf(h1[w][k], W2[l * HD + k], acc2);
  out[n * HD + l] = acc2;
}

// ---------------- y = x_src @ Wih.T ----------------

__global__ __launch_bounds__(256) void ygemm_kernel(const float* __restrict__ x,
    const float* __restrict__ Wih, float* __restrict__ y) {
  __shared__ __align__(16) float xs[16][HD];
  int w = threadIdx.x >> 6, l = threadIdx.x & 63;
  int n0 = blockIdx.x * 16;
  for (int r = threadIdx.x; r < 16 * HD; r += 256) xs[r >> 6][r & 63] = x[n0 * HD + r];
  __syncthreads();
  int j = w * 64 + l;
  float4 wr[16];
  const float4* W4 = (const float4*)(Wih + j * HD);
#pragma unroll
  for (int kk = 0; kk < 16; ++kk) wr[kk] = W4[kk];
  for (int m = 0; m < 16; ++m) {
    float acc = 0.0f;
    const float4* xv4 = (const float4*)xs[m];
    float acc2 = 0.0f;
#pragma unroll
    for (int kk = 0; kk < 16; kk += 2) {
      float4 xv = xv4[kk], wv = wr[kk];
      acc = fmaf(wv.x, xv.x, acc); acc = fmaf(wv.y, xv.y, acc);
      acc = fmaf(wv.z, xv.z, acc); acc = fmaf(wv.w, xv.w, acc);
      float4 xv2 = xv4[kk + 1], wv2 = wr[kk + 1];
      acc2 = fmaf(wv2.x, xv2.x, acc2); acc2 = fmaf(wv2.y, xv2.y, acc2);
      acc2 = fmaf(wv2.z, xv2.z, acc2); acc2 = fmaf(wv2.w, xv2.w, acc2);
    }
    y[(n0 + m) * 256 + j] = acc + acc2;
  }
}

// ---------------- SAGE-LSTM aggregation ----------------

__global__ __launch_bounds__(256) void lstm_kernel(const int* __restrict__ nbr,
    const float* __restrict__ y, const float* __restrict__ Whh,
    const float* __restrict__ bih, const float* __restrict__ bhh, float* __restrict__ agg) {
  __shared__ __align__(16) float hS[4][HD];
  __shared__ __align__(16) float gS[4][4][HD];  // [gate][node][unit]
  __shared__ int nbS[4][MAXD];
  int w = threadIdx.x >> 6, l = threadIdx.x & 63;
  int n0 = blockIdx.x * 4;
  int j = w * 64 + l;
  float4 wr[16];
  const float4* W4 = (const float4*)(Whh + j * HD);
#pragma unroll
  for (int kk = 0; kk < 16; ++kk) wr[kk] = W4[kk];
  float bsum = bih[j] + bhh[j];
  if (threadIdx.x < 4 * MAXD)
    nbS[threadIdx.x / MAXD][threadIdx.x % MAXD] = nbr[n0 * MAXD + threadIdx.x];
  hS[w][l] = 0.0f;
  float c = 0.0f, h = 0.0f;
  __syncthreads();
  float yv[4];
#pragma unroll
  for (int m = 0; m < 4; ++m) {
    int nb = nbS[m][0];
    yv[m] = (nb >= 0) ? y[nb * 256 + j] : 0.0f;
  }
  for (int t = 0; t < MAXD; ++t) {
    float acc[4];
#pragma unroll
    for (int m = 0; m < 4; ++m) acc[m] = bsum + yv[m];
    if (t + 1 < MAXD) {
#pragma unroll
      for (int m = 0; m < 4; ++m) {
        int nb = nbS[m][t + 1];
        yv[m] = (nb >= 0) ? y[nb * 256 + j] : 0.0f;
      }
    }
#pragma unroll
    for (int kk = 0; kk < 16; ++kk) {
      float4 wv = wr[kk];
#pragma unroll
      for (int m = 0; m < 4; ++m) {
        float4 hv = ((const float4*)hS[m])[kk];
        acc[m] = fmaf(wv.x, hv.x, acc[m]);
        acc[m] = fmaf(wv.y, hv.y, acc[m]);
        acc[m] = fmaf(wv.z, hv.z, acc[m]);
        acc[m] = fmaf(wv.w, hv.w, acc[m]);
      }
    }
#pragma unroll
    for (int m = 0; m < 4; ++m) gS[w][m][l] = acc[m];
    __syncthreads();
    float gi = gS[0][w][l], gf = gS[1][w][l], gg = gS[2][w][l], go = gS[3][w][l];
    float i_ = sigmoidf_(gi), f_ = sigmoidf_(gf);
    float g_ = tanhf_(gg), o_ = sigmoidf_(go);
    c = fmaf(f_, c, i_ * g_);
    h = o_ * tanhf_(c);
    hS[w][l] = h;
    __syncthreads();
  }
  agg[(n0 + w) * HD + l] = h;
}

// ---------------- hetero mean + SAGE linear + residual + relu ----------------
// Block = 16 nodes, 4 waves. Wave w computes one of the 4 matrix products
// (WlA@aggA, WlB@aggB, WrA@x, WrB@x) with its 64x64 matrix row held in 16
// float4 registers (ygemm pattern); partials summed through LDS.

__global__ __launch_bounds__(256) void combine_kernel(
    const float* __restrict__ aggA, const float* __restrict__ aggB,
    const float* __restrict__ WlA, const float* __restrict__ blA, const float* __restrict__ WrA,
    const float* __restrict__ WlB, const float* __restrict__ blB, const float* __restrict__ WrB,
    const float* __restrict__ xin, int has_res, float* __restrict__ out) {
  __shared__ __align__(16) float4 tS[3][16][16];   // aggA / aggB / xin tiles
  __shared__ __align__(16) float pS[4][16][64];    // per-wave partials
  int tid = threadIdx.x, w = tid >> 6, l = tid & 63;
  int n0 = blockIdx.x * 16;
  // stage tiles (3 iterations, coalesced float4)
  {
    const float4* A4 = (const float4*)(aggA + (size_t)n0 * 64);
    const float4* B4 = (const float4*)(aggB + (size_t)n0 * 64);
    const float4* X4 = (const float4*)(xin + (size_t)n0 * 64);
    tS[0][tid >> 4][tid & 15] = A4[tid];
    tS[1][tid >> 4][tid & 15] = B4[tid];
    tS[2][tid >> 4][tid & 15] = X4[tid];
  }
  __syncthreads();
  const float* Wsel = (w == 0) ? WlA : (w == 1) ? WlB : (w == 2) ? WrA : WrB;
  const float4 (*tp)[16] = tS[(w == 0) ? 0 : (w == 1) ? 1 : 2];
  float4 wr[16];
  const float4* W4 = (const float4*)(Wsel + l * 64);
#pragma unroll
  for (int kk = 0; kk < 16; ++kk) wr[kk] = W4[kk];
  for (int m0 = 0; m0 < 16; m0 += 4) {
    float a0 = 0.f, a1 = 0.f, a2 = 0.f, a3 = 0.f;
#pragma unroll
    for (int kk = 0; kk < 16; ++kk) {
      float4 wv = wr[kk];
      a0 = fma4(wv, tp[m0 + 0][kk], a0);
      a1 = fma4(wv, tp[m0 + 1][kk], a1);
      a2 = fma4(wv, tp[m0 + 2][kk], a2);
      a3 = fma4(wv, tp[m0 + 3][kk], a3);
    }
    pS[w][m0 + 0][l] = a0;
    pS[w][m0 + 1][l] = a1;
    pS[w][m0 + 2][l] = a2;
    pS[w][m0 + 3][l] = a3;
  }
  __syncthreads();
  // finalize: 1024 outputs -> one float4 per thread
  int idx4 = tid * 4;
  int m = idx4 >> 6, l0 = idx4 & 63;
  float4 p0 = *(float4*)&pS[0][m][l0];
  float4 p1 = *(float4*)&pS[1][m][l0];
  float4 p2 = *(float4*)&pS[2][m][l0];
  float4 p3 = *(float4*)&pS[3][m][l0];
  float4 ba = *(const float4*)(blA + l0);
  float4 bb = *(const float4*)(blB + l0);
  float4 r = tS[2][m][l0 >> 2];
  float4 v;
  v.x = 0.5f * (p0.x + p1.x + p2.x + p3.x + ba.x + bb.x) + (has_res ? r.x : 0.f);
  v.y = 0.5f * (p0.y + p1.y + p2.y + p3.y + ba.y + bb.y) + (has_res ? r.y : 0.f);
  v.z = 0.5f * (p0.z + p1.z + p2.z + p3.z + ba.z + bb.z) + (has_res ? r.z : 0.f);
  v.w = 0.5f * (p0.w + p1.w + p2.w + p3.w + ba.w + bb.w) + (has_res ? r.w : 0.f);
  v.x = fmaxf(v.x, 0.f); v.y = fmaxf(v.y, 0.f);
  v.z = fmaxf(v.z, 0.f); v.w = fmaxf(v.w, 0.f);
  ((float4*)(out + (size_t)n0 * 64))[tid] = v;
}

// ---------------- edge head ----------------
// Block = 64 edges, 4 waves x 16 edges each (wave-private LDS rows).
// All GEMMs use per-thread register weight rows; no LDS weight staging.
// Row layout (128 floats): [0:64) se -> er ; [64:128) te -> h2.

__global__ __launch_bounds__(256) void edge_head_kernel(
    const int* __restrict__ esrc, const int* __restrict__ edst, const float* __restrict__ ea,
    const float* __restrict__ s3, const float* __restrict__ t3,
    const float* __restrict__ Wg1, const float* __restrict__ bg1,
    const float* __restrict__ Wg2, const float* __restrict__ bg2,
    const float* __restrict__ Wm1, const float* __restrict__ bm1,
    const float* __restrict__ Wm2, const float* __restrict__ bm2,
    const float* __restrict__ Wm3, const float* __restrict__ bm3,
    float* __restrict__ out) {
  __shared__ __align__(16) float4 xS[64][32];
  __shared__ __align__(16) float4 eaS[64][4];
  int tid = threadIdx.x, w = tid >> 6, l = tid & 63;
  int e0 = blockIdx.x * 64;
  for (int idx = tid; idx < 2048; idx += 256) {
    int e = idx >> 5, kk = idx & 31;
    float4 v;
    if (kk < 16) v = ((const float4*)(s3 + (size_t)esrc[e0 + e] * 64))[kk];
    else         v = ((const float4*)(t3 + (size_t)edst[e0 + e] * 64))[kk - 16];
    xS[e][kk] = v;
  }
  {
    int e = tid >> 2, kk = tid & 3;
    eaS[e][kk] = ((const float4*)(ea + (size_t)(e0 + e) * 16))[kk];
  }
  __syncthreads();
  // ---- phase 1: h1 = relu([se|te]@Wg1.T + bg1); p = h1@Wg2 + bg2; er = g*se+(1-g)*te
  {
    float4 wr[32];
    const float4* W4 = (const float4*)(Wg1 + l * 128);
#pragma unroll
    for (int kk = 0; kk < 32; ++kk) wr[kk] = W4[kk];
    float bg = bg1[l], w2 = Wg2[l], b2 = bg2[0];
    for (int m0 = 0; m0 < 16; m0 += 4) {
      int e = w * 16 + m0;
      float a0 = bg, a1 = bg, a2 = bg, a3 = bg;
#pragma unroll
      for (int kk = 0; kk < 32; ++kk) {
        float4 wv = wr[kk];
        a0 = fma4(wv, xS[e + 0][kk], a0);
        a1 = fma4(wv, xS[e + 1][kk], a1);
        a2 = fma4(wv, xS[e + 2][kk], a2);
        a3 = fma4(wv, xS[e + 3][kk], a3);
      }
      a0 = fmaxf(a0, 0.f) * w2; a1 = fmaxf(a1, 0.f) * w2;
      a2 = fmaxf(a2, 0.f) * w2; a3 = fmaxf(a3, 0.f) * w2;
#pragma unroll
      for (int off = 32; off; off >>= 1) {
        a0 += __shfl_xor(a0, off); a1 += __shfl_xor(a1, off);
        a2 += __shfl_xor(a2, off); a3 += __shfl_xor(a3, off);
      }
      float g0 = sigmoidf_(a0 + b2), g1 = sigmoidf_(a1 + b2);
      float g2 = sigmoidf_(a2 + b2), g3 = sigmoidf_(a3 + b2);
      float* r0 = (float*)xS[e + 0]; float* r1 = (float*)xS[e + 1];
      float* r2 = (float*)xS[e + 2]; float* r3 = (float*)xS[e + 3];
      r0[l] = fmaf(g0, r0[l] - r0[64 + l], r0[64 + l]);
      r1[l] = fmaf(g1, r1[l] - r1[64 + l], r1[64 + l]);
      r2[l] = fmaf(g2, r2[l] - r2[64 + l], r2[64 + l]);
      r3[l] = fmaf(g3, r3[l] - r3[64 + l], r3[64 + l]);
    }
  }
  __syncthreads();
  // ---- phase 2: h2 = relu([er|ea]@Wm1.T + bm1) -> stored in te half
  {
    float4 wr[20];
    const float4* W4 = (const float4*)(Wm1 + l * 80);
#pragma unroll
    for (int kk = 0; kk < 20; ++kk) wr[kk] = W4[kk];
    float bm = bm1[l];
    float h2v[16];
    for (int m0 = 0; m0 < 16; m0 += 4) {
      int e = w * 16 + m0;
      float a0 = bm, a1 = bm, a2 = bm, a3 = bm;
#pragma unroll
      for (int kk = 0; kk < 16; ++kk) {
        float4 wv = wr[kk];
        a0 = fma4(wv, xS[e + 0][kk], a0);
        a1 = fma4(wv, xS[e + 1][kk], a1);
        a2 = fma4(wv, xS[e + 2][kk], a2);
        a3 = fma4(wv, xS[e + 3][kk], a3);
      }
#pragma unroll
      for (int kk = 0; kk < 4; ++kk) {
        float4 wv = wr[16 + kk];
        a0 = fma4(wv, eaS[e + 0][kk], a0);
        a1 = fma4(wv, eaS[e + 1][kk], a1);
        a2 = fma4(wv, eaS[e + 2][kk], a2);
        a3 = fma4(wv, eaS[e + 3][kk], a3);
      }
      h2v[m0 + 0] = fmaxf(a0, 0.f); h2v[m0 + 1] = fmaxf(a1, 0.f);
      h2v[m0 + 2] = fmaxf(a2, 0.f); h2v[m0 + 3] = fmaxf(a3, 0.f);
    }
#pragma unroll
    for (int m = 0; m < 16; ++m) ((float*)xS[w * 16 + m])[64 + l] = h2v[m];
  }
  __syncthreads();
  // ---- phase 3: h3 = relu(h2@Wm2.T + bm2) (32 units); out = h3@Wm3.T + bm3 (2)
  {
    int half = l >> 5, j = l & 31;
    float4 wr[16];
    const float4* W4 = (const float4*)(Wm2 + j * 64);
#pragma unroll
    for (int kk = 0; kk < 16; ++kk) wr[kk] = W4[kk];
    float bm = bm2[j], w3a = Wm3[j], w3b = Wm3[32 + j];
    float b3a = bm3[0], b3b = bm3[1];
    for (int mg = 0; mg < 16; mg += 2) {
      int m = mg + half, e = w * 16 + m;
      float acc = bm;
#pragma unroll
      for (int kk = 0; kk < 16; ++kk) acc = fma4(wr[kk], xS[e][16 + kk], acc);
      float h3 = fmaxf(acc, 0.f);
      float p0 = h3 * w3a, p1 = h3 * w3b;
#pragma unroll
      for (int off = 16; off; off >>= 1) {
        p0 += __shfl_xor(p0, off);
        p1 += __shfl_xor(p1, off);
      }
      if (j == 0) {
        int ge = e0 + e;
        out[ge * 2 + 0] = p0 + b3a;
        out[ge * 2 + 1] = p1 + b3b;
      }
    }
  }
}

// ---------------- host orchestration ----------------

extern "C" void kernel_launch(void* const* d_in, const int* in_sizes, int n_in, void* d_out,
                              int out_size, void* d_ws, size_t ws_size, hipStream_t stream) {
  const float* x_source = (const float*)d_in[0];
  const float* x_target = (const float*)d_in[1];
  const int* edges = (const int*)d_in[2];
  const float* edge_attr = (const float*)d_in[3];
  const float* We_s1 = (const float*)d_in[4];
  const float* be_s1 = (const float*)d_in[5];
  const float* We_s2 = (const float*)d_in[6];
  const float* be_s2 = (const float*)d_in[7];
  const float* We_t1 = (const float*)d_in[8];
  const float* be_t1 = (const float*)d_in[9];
  const float* We_t2 = (const float*)d_in[10];
  const float* be_t2 = (const float*)d_in[11];
  const float* Wih = (const float*)d_in[12];
  const float* Whh = (const float*)d_in[13];
  const float* bih = (const float*)d_in[14];
  const float* bhh = (const float*)d_in[15];
  const float* Wl = (const float*)d_in[16];
  const float* bl = (const float*)d_in[17];
  const float* Wr = (const float*)d_in[18];
  const float* Wg1 = (const float*)d_in[19];
  const float* bg1 = (const float*)d_in[20];
  const float* Wg2 = (const float*)d_in[21];
  const float* bg2 = (const float*)d_in[22];
  const float* Wm1 = (const float*)d_in[23];
  const float* bm1 = (const float*)d_in[24];
  const float* Wm2 = (const float*)d_in[25];
  const float* bm2 = (const float*)d_in[26];
  const float* Wm3 = (const float*)d_in[27];
  const float* bm3 = (const float*)d_in[28];
  float* out = (float*)d_out;

  int* nbr = (int*)d_ws;                       // 4*N*12
  int* cnt = nbr + 4 * N_NODES * MAXD;         // 4*N
  int* pool = cnt + 4 * N_NODES;               // 4*N*CAP
  float* fb = (float*)(pool + 4 * N_NODES * CAP);
  float* bufS[2] = {fb, fb + N_NODES * HD};
  float* bufT[2] = {fb + 2 * N_NODES * HD, fb + 3 * N_NODES * HD};
  float* agg[4];
  for (int i = 0; i < 4; ++i) agg[i] = fb + (size_t)(4 + i) * N_NODES * HD;
  float* y = fb + (size_t)8 * N_NODES * HD;    // N*256

  hipMemsetAsync(cnt, 0, 4 * N_NODES * sizeof(int), stream);
  scatter_kernel<<<(4 * N_EDGES + 255) / 256, 256, 0, stream>>>(edges, cnt, pool);
  sortrows_kernel<<<(4 * N_NODES + 63) / 64, 64, 0, stream>>>(cnt, pool, nbr);
  encode_kernel<32><<<N_NODES / 4, 256, 0, stream>>>(x_source, We_s1, be_s1, We_s2, be_s2, bufS[0]);
  encode_kernel<24><<<N_NODES / 4, 256, 0, stream>>>(x_target, We_t1, be_t1, We_t2, be_t2, bufT[0]);

  int cs = 0, ct = 0;
  for (int L = 0; L < 3; ++L) {
    for (int et = 0; et < 4; ++et) {
      int i = L * 4 + et;
      const float* xsrc = (et == 0 || et == 2) ? bufS[cs] : bufT[ct];
      ygemm_kernel<<<N_NODES / 16, 256, 0, stream>>>(xsrc, Wih + (size_t)i * 256 * 64, y);
      lstm_kernel<<<N_NODES / 4, 256, 0, stream>>>(nbr + et * N_NODES * MAXD, y,
          Whh + (size_t)i * 256 * 64, bih + i * 256, bhh + i * 256, agg[et]);
    }
    int i0 = L * 4 + 0, i1 = L * 4 + 1, i2 = L * 4 + 2, i3 = L * 4 + 3;
    combine_kernel<<<N_NODES / 16, 256, 0, stream>>>(agg[0], agg[3],
        Wl + i0 * 4096, bl + i0 * 64, Wr + i0 * 4096,
        Wl + i3 * 4096, bl + i3 * 64, Wr + i3 * 4096,
        bufS[cs], L > 0 ? 1 : 0, bufS[1 - cs]);
    combine_kernel<<<N_NODES / 16, 256, 0, stream>>>(agg[1], agg[2],
        Wl + i1 * 4096, bl + i1 * 64, Wr + i1 * 4096,
        Wl + i2 * 4096, bl + i2 * 64, Wr + i2 * 4096,
        bufT[ct], L > 0 ? 1 : 0, bufT[1 - ct]);
    cs = 1 - cs;
    ct = 1 - ct;
  }

  edge_head_kernel<<<N_EDGES / 64, 256, 0, stream>>>(edges + 4 * N_EDGES, edges + 5 * N_EDGES,
      edge_attr, bufS[cs], bufT[ct], Wg1, bg1, Wg2, bg2, Wm1, bm1, Wm2, bm2, Wm3, bm3, out);
}

// Round 3
// 1057.617 us; speedup vs baseline: 2.4335x; 1.8094x over previous
//
#include <hip/hip_runtime.h>

#define N_NODES 10000
#define N_EDGES 40000
#define HD 64
#define MAXD 12
#define CAP 32

typedef __attribute__((ext_vector_type(8))) short short8;
typedef __attribute__((ext_vector_type(4))) float floatx4;

__device__ __forceinline__ float sigmoidf_(float x) {
  return 1.0f / (1.0f + __expf(-x));
}
__device__ __forceinline__ float tanhf_(float x) {
  float ax = fabsf(x);
  float t = __expf(-2.0f * ax);
  float r = (1.0f - t) / (1.0f + t);
  return copysignf(r, x);
}
__device__ __forceinline__ float fma4(float4 w, float4 x, float a) {
  a = fmaf(w.x, x.x, a);
  a = fmaf(w.y, x.y, a);
  a = fmaf(w.z, x.z, a);
  return fmaf(w.w, x.w, a);
}

// split 8 consecutive fp32 into bf16 hi/lo fragments (truncation split; hi+lo
// captures ~16 mantissa bits -> 3-product MFMA gives ~2^-16 relative error)
__device__ __forceinline__ void split_frag(float4 a, float4 b, short8& hi, short8& lo) {
  float f[8] = {a.x, a.y, a.z, a.w, b.x, b.y, b.z, b.w};
  union { short8 v; unsigned d[4]; } H, L;
#pragma unroll
  for (int p = 0; p < 4; ++p) {
    unsigned u0 = __float_as_uint(f[2 * p]);
    unsigned u1 = __float_as_uint(f[2 * p + 1]);
    H.d[p] = (u0 >> 16) | (u1 & 0xFFFF0000u);
    float l0 = f[2 * p] - __uint_as_float(u0 & 0xFFFF0000u);
    float l1 = f[2 * p + 1] - __uint_as_float(u1 & 0xFFFF0000u);
    L.d[p] = (__float_as_uint(l0) >> 16) | (__float_as_uint(l1) & 0xFFFF0000u);
  }
  hi = H.v;
  lo = L.v;
}

// ---------------- adjacency build ----------------

__global__ void scatter_kernel(const int* __restrict__ edges, int* __restrict__ cnt,
                               int* __restrict__ pool) {
  int idx = blockIdx.x * 256 + threadIdx.x;
  if (idx >= 4 * N_EDGES) return;
  int et = idx / N_EDGES, e = idx - et * N_EDGES;
  int src = edges[(et * 2) * N_EDGES + e];
  int dst = edges[(et * 2 + 1) * N_EDGES + e];
  int slot = atomicAdd(&cnt[et * N_NODES + dst], 1);
  if (slot < CAP) pool[(et * N_NODES + dst) * CAP + slot] = src;
}

__global__ void sortrows_kernel(const int* __restrict__ cnt, const int* __restrict__ pool,
                                int* __restrict__ nbr) {
  __shared__ int buf[64][CAP + 1];
  int idx = blockIdx.x * 64 + threadIdx.x;
  if (idx >= 4 * N_NODES) return;
  int n = idx % N_NODES;
  int c = cnt[idx];
  if (c > CAP) c = CAP;
  int* a = buf[threadIdx.x];
  const int* row = pool + idx * CAP;
  for (int j = 0; j < c; ++j) a[j] = row[j] * 2;
  a[c] = n * 2 + 1;  // self loop sorts after equal-src originals (stable argsort semantics)
  ++c;
  for (int i2 = 1; i2 < c; ++i2) {
    int key = a[i2];
    int b = i2 - 1;
    while (b >= 0 && a[b] > key) { a[b + 1] = a[b]; --b; }
    a[b + 1] = key;
  }
  int* onbr = nbr + idx * MAXD;
  for (int t = 0; t < MAXD; ++t) onbr[t] = (t < c) ? (a[t] >> 1) : -1;
}

// ---------------- Whh -> fragment-ordered bf16 hi/lo ----------------
// frag combo = ((i*4 + w)*4 + g)*2 + kc ; per combo: hi block then lo block,
// each 64 lanes x 8 shorts. B layout (gemm_bt): lane n=l&15 holds row
// gate=g*64+16w+n, k = kc*32 + (l>>4)*8 + j (contiguous in Whh row).

__global__ __launch_bounds__(256) void prep_whh_kernel(const float* __restrict__ Whh,
                                                       short* __restrict__ whh16) {
  int gid = blockIdx.x * 256 + threadIdx.x;
  if (gid >= 384 * 64) return;
  int lane = gid & 63;
  int combo = gid >> 6;
  int kc = combo & 1;
  int g = (combo >> 1) & 3;
  int w = (combo >> 3) & 3;
  int i = combo >> 5;
  int gate = g * 64 + w * 16 + (lane & 15);
  int k0 = kc * 32 + (lane >> 4) * 8;
  const float* src = Whh + ((size_t)i * 256 + gate) * 64 + k0;
  float4 a = ((const float4*)src)[0];
  float4 b = ((const float4*)src)[1];
  short8 hi, lo;
  split_frag(a, b, hi, lo);
  short8* dst = (short8*)whh16;
  dst[(combo * 2 + 0) * 64 + lane] = hi;
  dst[(combo * 2 + 1) * 64 + lane] = lo;
}

// ---------------- node encoders ----------------

template <int IN>
__global__ __launch_bounds__(256) void encode_kernel(const float* __restrict__ x,
    const float* __restrict__ W1, const float* __restrict__ b1,
    const float* __restrict__ W2, const float* __restrict__ b2, float* __restrict__ out) {
  __shared__ float xs[4][IN];
  __shared__ float h1[4][HD];
  int w = threadIdx.x >> 6, l = threadIdx.x & 63;
  int n = blockIdx.x * 4 + w;
  if (l < IN) xs[w][l] = x[n * IN + l];
  __syncthreads();
  float acc = b1[l];
#pragma unroll
  for (int k = 0; k < IN; ++k) acc = fmaf(xs[w][k], W1[l * IN + k], acc);
  h1[w][l] = fmaxf(acc, 0.0f);
  __syncthreads();
  float acc2 = b2[l];
#pragma unroll
  for (int k = 0; k < HD; ++k) acc2 = fmaf(h1[w][k], W2[l * HD + k], acc2);
  out[n * HD + l] = acc2;
}

// ---------------- y = x_src @ Wih.T ----------------

__global__ __launch_bounds__(256) void ygemm_kernel(const float* __restrict__ x,
    const float* __restrict__ Wih, float* __restrict__ y) {
  __shared__ __align__(16) float xs[16][HD];
  int w = threadIdx.x >> 6, l = threadIdx.x & 63;
  int n0 = blockIdx.x * 16;
  for (int r = threadIdx.x; r < 16 * HD; r += 256) xs[r >> 6][r & 63] = x[n0 * HD + r];
  __syncthreads();
  int j = w * 64 + l;
  float4 wr[16];
  const float4* W4 = (const float4*)(Wih + j * HD);
#pragma unroll
  for (int kk = 0; kk < 16; ++kk) wr[kk] = W4[kk];
  for (int m = 0; m < 16; ++m) {
    float acc = 0.0f;
    const float4* xv4 = (const float4*)xs[m];
    float acc2 = 0.0f;
#pragma unroll
    for (int kk = 0; kk < 16; kk += 2) {
      float4 xv = xv4[kk], wv = wr[kk];
      acc = fmaf(wv.x, xv.x, acc); acc = fmaf(wv.y, xv.y, acc);
      acc = fmaf(wv.z, xv.z, acc); acc = fmaf(wv.w, xv.w, acc);
      float4 xv2 = xv4[kk + 1], wv2 = wr[kk + 1];
      acc2 = fmaf(wv2.x, xv2.x, acc2); acc2 = fmaf(wv2.y, xv2.y, acc2);
      acc2 = fmaf(wv2.z, xv2.z, acc2); acc2 = fmaf(wv2.w, xv2.w, acc2);
    }
    y[(n0 + m) * 256 + j] = acc + acc2;
  }
}

// ---------------- SAGE-LSTM aggregation, MFMA split-bf16 ----------------
// Block = 256 thr = 4 waves = 16 nodes (M=16). Wave w owns units
// [16w,16w+16) for ALL 4 gate types (N-tiles g*64+16w). Gate i/f/g/o for a
// (node,unit) land in one lane's acc regs -> c,h stay in registers.
// Per step: acc = y(C-init) + Whi*hhi + Whi*hlo + Wlo*hhi (24 MFMA/wave).

__global__ __launch_bounds__(256) void lstm_mfma_kernel(const int* __restrict__ nbr,
    const float* __restrict__ y, const short* __restrict__ whh16,
    const float* __restrict__ bih, const float* __restrict__ bhh, float* __restrict__ agg) {
  __shared__ __align__(16) float hS[2][16][68];
  __shared__ int nbS[16][MAXD];
  int tid = threadIdx.x, w = tid >> 6, l = tid & 63;
  int quad = l >> 4, n = l & 15;
  int n0 = blockIdx.x * 16;
  if (tid < 16 * MAXD) nbS[tid / MAXD][tid % MAXD] = nbr[n0 * MAXD + tid];
  // B fragments (const across steps): Bh/Bl[g][kc]
  short8 Bh[4][2], Bl[4][2];
  {
    const short8* wf = (const short8*)whh16;
#pragma unroll
    for (int g = 0; g < 4; ++g)
#pragma unroll
      for (int kc = 0; kc < 2; ++kc) {
        int combo = (w * 4 + g) * 2 + kc;
        Bh[g][kc] = wf[(combo * 2 + 0) * 64 + l];
        Bl[g][kc] = wf[(combo * 2 + 1) * 64 + l];
      }
  }
  float bs[4];
#pragma unroll
  for (int g = 0; g < 4; ++g) {
    int u = g * 64 + w * 16 + n;
    bs[g] = bih[u] + bhh[u];
  }
  float c[4] = {0.f, 0.f, 0.f, 0.f}, h[4] = {0.f, 0.f, 0.f, 0.f};
  short8 Ah[2], Al[2];
#pragma unroll
  for (int kc = 0; kc < 2; ++kc) { Ah[kc] = (short8)0; Al[kc] = (short8)0; }
  __syncthreads();
  // prefetch y for t=0
  float yv[4][4];
  {
    int nbq[4];
#pragma unroll
    for (int r = 0; r < 4; ++r) nbq[r] = nbS[quad * 4 + r][0];
#pragma unroll
    for (int g = 0; g < 4; ++g)
#pragma unroll
      for (int r = 0; r < 4; ++r) {
        float v = 0.f;
        if (nbq[r] >= 0) v = y[(size_t)nbq[r] * 256 + g * 64 + w * 16 + n];
        yv[g][r] = v;
      }
  }
  for (int t = 0; t < MAXD; ++t) {
    floatx4 acc[4];
#pragma unroll
    for (int g = 0; g < 4; ++g) {
      floatx4 a = {yv[g][0], yv[g][1], yv[g][2], yv[g][3]};
      a = __builtin_amdgcn_mfma_f32_16x16x32_bf16(Ah[0], Bh[g][0], a, 0, 0, 0);
      a = __builtin_amdgcn_mfma_f32_16x16x32_bf16(Ah[1], Bh[g][1], a, 0, 0, 0);
      a = __builtin_amdgcn_mfma_f32_16x16x32_bf16(Al[0], Bh[g][0], a, 0, 0, 0);
      a = __builtin_amdgcn_mfma_f32_16x16x32_bf16(Al[1], Bh[g][1], a, 0, 0, 0);
      a = __builtin_amdgcn_mfma_f32_16x16x32_bf16(Ah[0], Bl[g][0], a, 0, 0, 0);
      a = __builtin_amdgcn_mfma_f32_16x16x32_bf16(Ah[1], Bl[g][1], a, 0, 0, 0);
      acc[g] = a;
    }
    int buf = (t + 1) & 1;
#pragma unroll
    for (int r = 0; r < 4; ++r) {
      float gi = acc[0][r] + bs[0];
      float gf = acc[1][r] + bs[1];
      float gg = acc[2][r] + bs[2];
      float go = acc[3][r] + bs[3];
      c[r] = fmaf(sigmoidf_(gf), c[r], sigmoidf_(gi) * tanhf_(gg));
      h[r] = sigmoidf_(go) * tanhf_(c[r]);
      hS[buf][quad * 4 + r][w * 16 + n] = h[r];
    }
    __syncthreads();
    if (t + 1 < MAXD) {
      // A-frags: lane m = l&15, k = kc*32 + quad*8 + j (contiguous in hS row)
      const float* hp = &hS[buf][n][quad * 8];
      float4 q0 = *(const float4*)(hp);
      float4 q1 = *(const float4*)(hp + 4);
      float4 q2 = *(const float4*)(hp + 32);
      float4 q3 = *(const float4*)(hp + 36);
      split_frag(q0, q1, Ah[0], Al[0]);
      split_frag(q2, q3, Ah[1], Al[1]);
      int nbq[4];
#pragma unroll
      for (int r = 0; r < 4; ++r) nbq[r] = nbS[quad * 4 + r][t + 1];
#pragma unroll
      for (int g = 0; g < 4; ++g)
#pragma unroll
        for (int r = 0; r < 4; ++r) {
          float v = 0.f;
          if (nbq[r] >= 0) v = y[(size_t)nbq[r] * 256 + g * 64 + w * 16 + n];
          yv[g][r] = v;
        }
    }
  }
#pragma unroll
  for (int r = 0; r < 4; ++r)
    agg[(size_t)(n0 + quad * 4 + r) * HD + w * 16 + n] = h[r];
}

// ---------------- hetero mean + SAGE linear + residual + relu ----------------

__global__ __launch_bounds__(256) void combine_kernel(
    const float* __restrict__ aggA, const float* __restrict__ aggB,
    const float* __restrict__ WlA, const float* __restrict__ blA, const float* __restrict__ WrA,
    const float* __restrict__ WlB, const float* __restrict__ blB, const float* __restrict__ WrB,
    const float* __restrict__ xin, int has_res, float* __restrict__ out) {
  __shared__ __align__(16) float4 tS[3][16][16];
  __shared__ __align__(16) float pS[4][16][64];
  int tid = threadIdx.x, w = tid >> 6, l = tid & 63;
  int n0 = blockIdx.x * 16;
  {
    const float4* A4 = (const float4*)(aggA + (size_t)n0 * 64);
    const float4* B4 = (const float4*)(aggB + (size_t)n0 * 64);
    const float4* X4 = (const float4*)(xin + (size_t)n0 * 64);
    tS[0][tid >> 4][tid & 15] = A4[tid];
    tS[1][tid >> 4][tid & 15] = B4[tid];
    tS[2][tid >> 4][tid & 15] = X4[tid];
  }
  __syncthreads();
  const float* Wsel = (w == 0) ? WlA : (w == 1) ? WlB : (w == 2) ? WrA : WrB;
  const float4 (*tp)[16] = tS[(w == 0) ? 0 : (w == 1) ? 1 : 2];
  float4 wr[16];
  const float4* W4 = (const float4*)(Wsel + l * 64);
#pragma unroll
  for (int kk = 0; kk < 16; ++kk) wr[kk] = W4[kk];
  for (int m0 = 0; m0 < 16; m0 += 4) {
    float a0 = 0.f, a1 = 0.f, a2 = 0.f, a3 = 0.f;
#pragma unroll
    for (int kk = 0; kk < 16; ++kk) {
      float4 wv = wr[kk];
      a0 = fma4(wv, tp[m0 + 0][kk], a0);
      a1 = fma4(wv, tp[m0 + 1][kk], a1);
      a2 = fma4(wv, tp[m0 + 2][kk], a2);
      a3 = fma4(wv, tp[m0 + 3][kk], a3);
    }
    pS[w][m0 + 0][l] = a0;
    pS[w][m0 + 1][l] = a1;
    pS[w][m0 + 2][l] = a2;
    pS[w][m0 + 3][l] = a3;
  }
  __syncthreads();
  int idx4 = tid * 4;
  int m = idx4 >> 6, l0 = idx4 & 63;
  float4 p0 = *(float4*)&pS[0][m][l0];
  float4 p1 = *(float4*)&pS[1][m][l0];
  float4 p2 = *(float4*)&pS[2][m][l0];
  float4 p3 = *(float4*)&pS[3][m][l0];
  float4 ba = *(const float4*)(blA + l0);
  float4 bb = *(const float4*)(blB + l0);
  float4 r = tS[2][m][l0 >> 2];
  float4 v;
  v.x = 0.5f * (p0.x + p1.x + p2.x + p3.x + ba.x + bb.x) + (has_res ? r.x : 0.f);
  v.y = 0.5f * (p0.y + p1.y + p2.y + p3.y + ba.y + bb.y) + (has_res ? r.y : 0.f);
  v.z = 0.5f * (p0.z + p1.z + p2.z + p3.z + ba.z + bb.z) + (has_res ? r.z : 0.f);
  v.w = 0.5f * (p0.w + p1.w + p2.w + p3.w + ba.w + bb.w) + (has_res ? r.w : 0.f);
  v.x = fmaxf(v.x, 0.f); v.y = fmaxf(v.y, 0.f);
  v.z = fmaxf(v.z, 0.f); v.w = fmaxf(v.w, 0.f);
  ((float4*)(out + (size_t)n0 * 64))[tid] = v;
}

// ---------------- edge head ----------------

__global__ __launch_bounds__(256) void edge_head_kernel(
    const int* __restrict__ esrc, const int* __restrict__ edst, const float* __restrict__ ea,
    const float* __restrict__ s3, const float* __restrict__ t3,
    const float* __restrict__ Wg1, const float* __restrict__ bg1,
    const float* __restrict__ Wg2, const float* __restrict__ bg2,
    const float* __restrict__ Wm1, const float* __restrict__ bm1,
    const float* __restrict__ Wm2, const float* __restrict__ bm2,
    const float* __restrict__ Wm3, const float* __restrict__ bm3,
    float* __restrict__ out) {
  __shared__ __align__(16) float4 xS[64][32];
  __shared__ __align__(16) float4 eaS[64][4];
  int tid = threadIdx.x, w = tid >> 6, l = tid & 63;
  int e0 = blockIdx.x * 64;
  for (int idx = tid; idx < 2048; idx += 256) {
    int e = idx >> 5, kk = idx & 31;
    float4 v;
    if (kk < 16) v = ((const float4*)(s3 + (size_t)esrc[e0 + e] * 64))[kk];
    else         v = ((const float4*)(t3 + (size_t)edst[e0 + e] * 64))[kk - 16];
    xS[e][kk] = v;
  }
  {
    int e = tid >> 2, kk = tid & 3;
    eaS[e][kk] = ((const float4*)(ea + (size_t)(e0 + e) * 16))[kk];
  }
  __syncthreads();
  {
    float4 wr[32];
    const float4* W4 = (const float4*)(Wg1 + l * 128);
#pragma unroll
    for (int kk = 0; kk < 32; ++kk) wr[kk] = W4[kk];
    float bg = bg1[l], w2 = Wg2[l], b2 = bg2[0];
    for (int m0 = 0; m0 < 16; m0 += 4) {
      int e = w * 16 + m0;
      float a0 = bg, a1 = bg, a2 = bg, a3 = bg;
#pragma unroll
      for (int kk = 0; kk < 32; ++kk) {
        float4 wv = wr[kk];
        a0 = fma4(wv, xS[e + 0][kk], a0);
        a1 = fma4(wv, xS[e + 1][kk], a1);
        a2 = fma4(wv, xS[e + 2][kk], a2);
        a3 = fma4(wv, xS[e + 3][kk], a3);
      }
      a0 = fmaxf(a0, 0.f) * w2; a1 = fmaxf(a1, 0.f) * w2;
      a2 = fmaxf(a2, 0.f) * w2; a3 = fmaxf(a3, 0.f) * w2;
#pragma unroll
      for (int off = 32; off; off >>= 1) {
        a0 += __shfl_xor(a0, off); a1 += __shfl_xor(a1, off);
        a2 += __shfl_xor(a2, off); a3 += __shfl_xor(a3, off);
      }
      float g0 = sigmoidf_(a0 + b2), g1 = sigmoidf_(a1 + b2);
      float g2 = sigmoidf_(a2 + b2), g3 = sigmoidf_(a3 + b2);
      float* r0 = (float*)xS[e + 0]; float* r1 = (float*)xS[e + 1];
      float* r2 = (float*)xS[e + 2]; float* r3 = (float*)xS[e + 3];
      r0[l] = fmaf(g0, r0[l] - r0[64 + l], r0[64 + l]);
      r1[l] = fmaf(g1, r1[l] - r1[64 + l], r1[64 + l]);
      r2[l] = fmaf(g2, r2[l] - r2[64 + l], r2[64 + l]);
      r3[l] = fmaf(g3, r3[l] - r3[64 + l], r3[64 + l]);
    }
  }
  __syncthreads();
  {
    float4 wr[20];
    const float4* W4 = (const float4*)(Wm1 + l * 80);
#pragma unroll
    for (int kk = 0; kk < 20; ++kk) wr[kk] = W4[kk];
    float bm = bm1[l];
    float h2v[16];
    for (int m0 = 0; m0 < 16; m0 += 4) {
      int e = w * 16 + m0;
      float a0 = bm, a1 = bm, a2 = bm, a3 = bm;
#pragma unroll
      for (int kk = 0; kk < 16; ++kk) {
        float4 wv = wr[kk];
        a0 = fma4(wv, xS[e + 0][kk], a0);
        a1 = fma4(wv, xS[e + 1][kk], a1);
        a2 = fma4(wv, xS[e + 2][kk], a2);
        a3 = fma4(wv, xS[e + 3][kk], a3);
      }
#pragma unroll
      for (int kk = 0; kk < 4; ++kk) {
        float4 wv = wr[16 + kk];
        a0 = fma4(wv, eaS[e + 0][kk], a0);
        a1 = fma4(wv, eaS[e + 1][kk], a1);
        a2 = fma4(wv, eaS[e + 2][kk], a2);
        a3 = fma4(wv, eaS[e + 3][kk], a3);
      }
      h2v[m0 + 0] = fmaxf(a0, 0.f); h2v[m0 + 1] = fmaxf(a1, 0.f);
      h2v[m0 + 2] = fmaxf(a2, 0.f); h2v[m0 + 3] = fmaxf(a3, 0.f);
    }
#pragma unroll
    for (int m = 0; m < 16; ++m) ((float*)xS[w * 16 + m])[64 + l] = h2v[m];
  }
  __syncthreads();
  {
    int half = l >> 5, j = l & 31;
    float4 wr[16];
    const float4* W4 = (const float4*)(Wm2 + j * 64);
#pragma unroll
    for (int kk = 0; kk < 16; ++kk) wr[kk] = W4[kk];
    float bm = bm2[j], w3a = Wm3[j], w3b = Wm3[32 + j];
    float b3a = bm3[0], b3b = bm3[1];
    for (int mg = 0; mg < 16; mg += 2) {
      int m = mg + half, e = w * 16 + m;
      float acc = bm;
#pragma unroll
      for (int kk = 0; kk < 16; ++kk) acc = fma4(wr[kk], xS[e][16 + kk], acc);
      float h3 = fmaxf(acc, 0.f);
      float p0 = h3 * w3a, p1 = h3 * w3b;
#pragma unroll
      for (int off = 16; off; off >>= 1) {
        p0 += __shfl_xor(p0, off);
        p1 += __shfl_xor(p1, off);
      }
      if (j == 0) {
        int ge = e0 + e;
        out[ge * 2 + 0] = p0 + b3a;
        out[ge * 2 + 1] = p1 + b3b;
      }
    }
  }
}

// ---------------- host orchestration ----------------

extern "C" void kernel_launch(void* const* d_in, const int* in_sizes, int n_in, void* d_out,
                              int out_size, void* d_ws, size_t ws_size, hipStream_t stream) {
  const float* x_source = (const float*)d_in[0];
  const float* x_target = (const float*)d_in[1];
  const int* edges = (const int*)d_in[2];
  const float* edge_attr = (const float*)d_in[3];
  const float* We_s1 = (const float*)d_in[4];
  const float* be_s1 = (const float*)d_in[5];
  const float* We_s2 = (const float*)d_in[6];
  const float* be_s2 = (const float*)d_in[7];
  const float* We_t1 = (const float*)d_in[8];
  const float* be_t1 = (const float*)d_in[9];
  const float* We_t2 = (const float*)d_in[10];
  const float* be_t2 = (const float*)d_in[11];
  const float* Wih = (const float*)d_in[12];
  const float* Whh = (const float*)d_in[13];
  const float* bih = (const float*)d_in[14];
  const float* bhh = (const float*)d_in[15];
  const float* Wl = (const float*)d_in[16];
  const float* bl = (const float*)d_in[17];
  const float* Wr = (const float*)d_in[18];
  const float* Wg1 = (const float*)d_in[19];
  const float* bg1 = (const float*)d_in[20];
  const float* Wg2 = (const float*)d_in[21];
  const float* bg2 = (const float*)d_in[22];
  const float* Wm1 = (const float*)d_in[23];
  const float* bm1 = (const float*)d_in[24];
  const float* Wm2 = (const float*)d_in[25];
  const float* bm2 = (const float*)d_in[26];
  const float* Wm3 = (const float*)d_in[27];
  const float* bm3 = (const float*)d_in[28];
  float* out = (float*)d_out;

  int* nbr = (int*)d_ws;                       // 4*N*12
  int* cnt = nbr + 4 * N_NODES * MAXD;         // 4*N
  int* pool = cnt + 4 * N_NODES;               // 4*N*CAP
  float* fb = (float*)(pool + 4 * N_NODES * CAP);
  float* bufS[2] = {fb, fb + N_NODES * HD};
  float* bufT[2] = {fb + 2 * N_NODES * HD, fb + 3 * N_NODES * HD};
  float* agg[4];
  for (int i = 0; i < 4; ++i) agg[i] = fb + (size_t)(4 + i) * N_NODES * HD;
  float* y = fb + (size_t)8 * N_NODES * HD;    // N*256
  short* whh16 = (short*)(y + (size_t)N_NODES * 256);  // 12 * 32768 shorts

  hipMemsetAsync(cnt, 0, 4 * N_NODES * sizeof(int), stream);
  prep_whh_kernel<<<96, 256, 0, stream>>>(Whh, whh16);
  scatter_kernel<<<(4 * N_EDGES + 255) / 256, 256, 0, stream>>>(edges, cnt, pool);
  sortrows_kernel<<<(4 * N_NODES + 63) / 64, 64, 0, stream>>>(cnt, pool, nbr);
  encode_kernel<32><<<N_NODES / 4, 256, 0, stream>>>(x_source, We_s1, be_s1, We_s2, be_s2, bufS[0]);
  encode_kernel<24><<<N_NODES / 4, 256, 0, stream>>>(x_target, We_t1, be_t1, We_t2, be_t2, bufT[0]);

  int cs = 0, ct = 0;
  for (int L = 0; L < 3; ++L) {
    for (int et = 0; et < 4; ++et) {
      int i = L * 4 + et;
      const float* xsrc = (et == 0 || et == 2) ? bufS[cs] : bufT[ct];
      ygemm_kernel<<<N_NODES / 16, 256, 0, stream>>>(xsrc, Wih + (size_t)i * 256 * 64, y);
      lstm_mfma_kernel<<<N_NODES / 16, 256, 0, stream>>>(nbr + et * N_NODES * MAXD, y,
          whh16 + (size_t)i * 32768, bih + i * 256, bhh + i * 256, agg[et]);
    }
    int i0 = L * 4 + 0, i1 = L * 4 + 1, i2 = L * 4 + 2, i3 = L * 4 + 3;
    combine_kernel<<<N_NODES / 16, 256, 0, stream>>>(agg[0], agg[3],
        Wl + i0 * 4096, bl + i0 * 64, Wr + i0 * 4096,
        Wl + i3 * 4096, bl + i3 * 64, Wr + i3 * 4096,
        bufS[cs], L > 0 ? 1 : 0, bufS[1 - cs]);
    combine_kernel<<<N_NODES / 16, 256, 0, stream>>>(agg[1], agg[2],
        Wl + i1 * 4096, bl + i1 * 64, Wr + i1 * 4096,
        Wl + i2 * 4096, bl + i2 * 64, Wr + i2 * 4096,
        bufT[ct], L > 0 ? 1 : 0, bufT[1 - ct]);
    cs = 1 - cs;
    ct = 1 - ct;
  }

  edge_head_kernel<<<N_EDGES / 64, 256, 0, stream>>>(edges + 4 * N_EDGES, edges + 5 * N_EDGES,
      edge_attr, bufS[cs], bufT[ct], Wg1, bg1, Wg2, bg2, Wm1, bm1, Wm2, bm2, Wm3, bm3, out);
}

// Round 4
// 798.451 us; speedup vs baseline: 3.2234x; 1.3246x over previous
//
#include <hip/hip_runtime.h>

#define N_NODES 10000
#define N_EDGES 40000
#define HD 64
#define MAXD 12
#define CAP 32

typedef __attribute__((ext_vector_type(8))) short short8;
typedef __attribute__((ext_vector_type(4))) float floatx4;

__device__ __forceinline__ float sigmoidf_(float x) {
  return 1.0f / (1.0f + __expf(-x));
}
__device__ __forceinline__ float tanhf_(float x) {
  float ax = fabsf(x);
  float t = __expf(-2.0f * ax);
  float r = (1.0f - t) / (1.0f + t);
  return copysignf(r, x);
}
__device__ __forceinline__ float fma4(float4 w, float4 x, float a) {
  a = fmaf(w.x, x.x, a);
  a = fmaf(w.y, x.y, a);
  a = fmaf(w.z, x.z, a);
  return fmaf(w.w, x.w, a);
}

// split 8 consecutive fp32 into bf16 hi/lo fragments
__device__ __forceinline__ void split_frag(float4 a, float4 b, short8& hi, short8& lo) {
  float f[8] = {a.x, a.y, a.z, a.w, b.x, b.y, b.z, b.w};
  union { short8 v; unsigned d[4]; } H, L;
#pragma unroll
  for (int p = 0; p < 4; ++p) {
    unsigned u0 = __float_as_uint(f[2 * p]);
    unsigned u1 = __float_as_uint(f[2 * p + 1]);
    H.d[p] = (u0 >> 16) | (u1 & 0xFFFF0000u);
    float l0 = f[2 * p] - __uint_as_float(u0 & 0xFFFF0000u);
    float l1 = f[2 * p + 1] - __uint_as_float(u1 & 0xFFFF0000u);
    L.d[p] = (__float_as_uint(l0) >> 16) | (__float_as_uint(l1) & 0xFFFF0000u);
  }
  hi = H.v;
  lo = L.v;
}

// ---------------- adjacency build ----------------

__global__ void scatter_kernel(const int* __restrict__ edges, int* __restrict__ cnt,
                               int* __restrict__ pool) {
  int idx = blockIdx.x * 256 + threadIdx.x;
  if (idx >= 4 * N_EDGES) return;
  int et = idx / N_EDGES, e = idx - et * N_EDGES;
  int src = edges[(et * 2) * N_EDGES + e];
  int dst = edges[(et * 2 + 1) * N_EDGES + e];
  int slot = atomicAdd(&cnt[et * N_NODES + dst], 1);
  if (slot < CAP) pool[(et * N_NODES + dst) * CAP + slot] = src;
}

__global__ void sortrows_kernel(const int* __restrict__ cnt, const int* __restrict__ pool,
                                int* __restrict__ nbr) {
  __shared__ int buf[64][CAP + 1];
  int idx = blockIdx.x * 64 + threadIdx.x;
  if (idx >= 4 * N_NODES) return;
  int n = idx % N_NODES;
  int c = cnt[idx];
  if (c > CAP) c = CAP;
  int* a = buf[threadIdx.x];
  const int* row = pool + idx * CAP;
  for (int j = 0; j < c; ++j) a[j] = row[j] * 2;
  a[c] = n * 2 + 1;  // self loop sorts after equal-src originals (stable argsort semantics)
  ++c;
  for (int i2 = 1; i2 < c; ++i2) {
    int key = a[i2];
    int b = i2 - 1;
    while (b >= 0 && a[b] > key) { a[b + 1] = a[b]; --b; }
    a[b + 1] = key;
  }
  int* onbr = nbr + idx * MAXD;
  for (int t = 0; t < MAXD; ++t) onbr[t] = (t < c) ? (a[t] >> 1) : -1;
}

// ---------------- Whh -> fragment-ordered bf16 hi/lo ----------------

__global__ __launch_bounds__(256) void prep_whh_kernel(const float* __restrict__ Whh,
                                                       short* __restrict__ whh16) {
  int gid = blockIdx.x * 256 + threadIdx.x;
  if (gid >= 384 * 64) return;
  int lane = gid & 63;
  int combo = gid >> 6;
  int kc = combo & 1;
  int g = (combo >> 1) & 3;
  int w = (combo >> 3) & 3;
  int i = combo >> 5;
  int gate = g * 64 + w * 16 + (lane & 15);
  int k0 = kc * 32 + (lane >> 4) * 8;
  const float* src = Whh + ((size_t)i * 256 + gate) * 64 + k0;
  float4 a = ((const float4*)src)[0];
  float4 b = ((const float4*)src)[1];
  short8 hi, lo;
  split_frag(a, b, hi, lo);
  short8* dst = (short8*)whh16;
  dst[(combo * 2 + 0) * 64 + lane] = hi;
  dst[(combo * 2 + 1) * 64 + lane] = lo;
}

// ---------------- node encoders ----------------

template <int IN>
__global__ __launch_bounds__(256) void encode_kernel(const float* __restrict__ x,
    const float* __restrict__ W1, const float* __restrict__ b1,
    const float* __restrict__ W2, const float* __restrict__ b2, float* __restrict__ out) {
  __shared__ float xs[4][IN];
  __shared__ float h1[4][HD];
  int w = threadIdx.x >> 6, l = threadIdx.x & 63;
  int n = blockIdx.x * 4 + w;
  if (l < IN) xs[w][l] = x[n * IN + l];
  __syncthreads();
  float acc = b1[l];
#pragma unroll
  for (int k = 0; k < IN; ++k) acc = fmaf(xs[w][k], W1[l * IN + k], acc);
  h1[w][l] = fmaxf(acc, 0.0f);
  __syncthreads();
  float acc2 = b2[l];
#pragma unroll
  for (int k = 0; k < HD; ++k) acc2 = fmaf(h1[w][k], W2[l * HD + k], acc2);
  out[n * HD + l] = acc2;
}

// ---------------- y = x_src @ Wih.T, all 4 edge types of one layer ----------------

__global__ __launch_bounds__(256) void ygemm_kernel(const float* __restrict__ xs0,
    const float* __restrict__ xt0, const float* __restrict__ WihL, float* __restrict__ ybase) {
  __shared__ __align__(16) float xs[16][HD];
  int et = blockIdx.y;
  const float* x = (et == 0 || et == 2) ? xs0 : xt0;
  const float* Wih = WihL + (size_t)et * 16384;
  float* y = ybase + (size_t)et * N_NODES * 256;
  int w = threadIdx.x >> 6, l = threadIdx.x & 63;
  int n0 = blockIdx.x * 16;
  for (int r = threadIdx.x; r < 16 * HD; r += 256) xs[r >> 6][r & 63] = x[n0 * HD + r];
  __syncthreads();
  int j = w * 64 + l;
  float4 wr[16];
  const float4* W4 = (const float4*)(Wih + j * HD);
#pragma unroll
  for (int kk = 0; kk < 16; ++kk) wr[kk] = W4[kk];
  for (int m = 0; m < 16; ++m) {
    float acc = 0.0f;
    const float4* xv4 = (const float4*)xs[m];
    float acc2 = 0.0f;
#pragma unroll
    for (int kk = 0; kk < 16; kk += 2) {
      float4 xv = xv4[kk], wv = wr[kk];
      acc = fmaf(wv.x, xv.x, acc); acc = fmaf(wv.y, xv.y, acc);
      acc = fmaf(wv.z, xv.z, acc); acc = fmaf(wv.w, xv.w, acc);
      float4 xv2 = xv4[kk + 1], wv2 = wr[kk + 1];
      acc2 = fmaf(wv2.x, xv2.x, acc2); acc2 = fmaf(wv2.y, xv2.y, acc2);
      acc2 = fmaf(wv2.z, xv2.z, acc2); acc2 = fmaf(wv2.w, xv2.w, acc2);
    }
    y[(n0 + m) * 256 + j] = acc + acc2;
  }
}

// ---------------- SAGE-LSTM aggregation, MFMA split-bf16, 4 edge types ----------------
// grid = (625, 4); blockIdx.y = edge type. Block = 16 nodes, 4 waves.
// Wave w owns units [16w,16w+16) for all 4 gates -> i,f,g,o land in one lane.

__global__ __launch_bounds__(256) void lstm_mfma_kernel(const int* __restrict__ nbrAll,
    const float* __restrict__ ybase, const short* __restrict__ whh16L,
    const float* __restrict__ bihL, const float* __restrict__ bhhL, float* __restrict__ aggBase) {
  __shared__ __align__(16) float hS[2][16][68];
  __shared__ int nbS[16][MAXD];
  int et = blockIdx.y;
  const int* nbr = nbrAll + (size_t)et * N_NODES * MAXD;
  const float* y = ybase + (size_t)et * N_NODES * 256;
  const short* whh16 = whh16L + (size_t)et * 32768;
  const float* bih = bihL + et * 256;
  const float* bhh = bhhL + et * 256;
  float* agg = aggBase + (size_t)et * N_NODES * HD;
  int tid = threadIdx.x, w = tid >> 6, l = tid & 63;
  int quad = l >> 4, n = l & 15;
  int n0 = blockIdx.x * 16;
  if (tid < 16 * MAXD) nbS[tid / MAXD][tid % MAXD] = nbr[n0 * MAXD + tid];
  short8 Bh[4][2], Bl[4][2];
  {
    const short8* wf = (const short8*)whh16;
#pragma unroll
    for (int g = 0; g < 4; ++g)
#pragma unroll
      for (int kc = 0; kc < 2; ++kc) {
        int combo = (w * 4 + g) * 2 + kc;
        Bh[g][kc] = wf[(combo * 2 + 0) * 64 + l];
        Bl[g][kc] = wf[(combo * 2 + 1) * 64 + l];
      }
  }
  float bs[4];
#pragma unroll
  for (int g = 0; g < 4; ++g) {
    int u = g * 64 + w * 16 + n;
    bs[g] = bih[u] + bhh[u];
  }
  float c[4] = {0.f, 0.f, 0.f, 0.f}, h[4] = {0.f, 0.f, 0.f, 0.f};
  short8 Ah[2], Al[2];
#pragma unroll
  for (int kc = 0; kc < 2; ++kc) { Ah[kc] = (short8)0; Al[kc] = (short8)0; }
  __syncthreads();
  float yv[4][4];
  {
    int nbq[4];
#pragma unroll
    for (int r = 0; r < 4; ++r) nbq[r] = nbS[quad * 4 + r][0];
#pragma unroll
    for (int g = 0; g < 4; ++g)
#pragma unroll
      for (int r = 0; r < 4; ++r) {
        float v = 0.f;
        if (nbq[r] >= 0) v = y[(size_t)nbq[r] * 256 + g * 64 + w * 16 + n];
        yv[g][r] = v;
      }
  }
  for (int t = 0; t < MAXD; ++t) {
    floatx4 acc[4];
#pragma unroll
    for (int g = 0; g < 4; ++g) {
      floatx4 a = {yv[g][0], yv[g][1], yv[g][2], yv[g][3]};
      a = __builtin_amdgcn_mfma_f32_16x16x32_bf16(Ah[0], Bh[g][0], a, 0, 0, 0);
      a = __builtin_amdgcn_mfma_f32_16x16x32_bf16(Ah[1], Bh[g][1], a, 0, 0, 0);
      a = __builtin_amdgcn_mfma_f32_16x16x32_bf16(Al[0], Bh[g][0], a, 0, 0, 0);
      a = __builtin_amdgcn_mfma_f32_16x16x32_bf16(Al[1], Bh[g][1], a, 0, 0, 0);
      a = __builtin_amdgcn_mfma_f32_16x16x32_bf16(Ah[0], Bl[g][0], a, 0, 0, 0);
      a = __builtin_amdgcn_mfma_f32_16x16x32_bf16(Ah[1], Bl[g][1], a, 0, 0, 0);
      acc[g] = a;
    }
    int buf = (t + 1) & 1;
#pragma unroll
    for (int r = 0; r < 4; ++r) {
      float gi = acc[0][r] + bs[0];
      float gf = acc[1][r] + bs[1];
      float gg = acc[2][r] + bs[2];
      float go = acc[3][r] + bs[3];
      c[r] = fmaf(sigmoidf_(gf), c[r], sigmoidf_(gi) * tanhf_(gg));
      h[r] = sigmoidf_(go) * tanhf_(c[r]);
      hS[buf][quad * 4 + r][w * 16 + n] = h[r];
    }
    __syncthreads();
    if (t + 1 < MAXD) {
      const float* hp = &hS[buf][n][quad * 8];
      float4 q0 = *(const float4*)(hp);
      float4 q1 = *(const float4*)(hp + 4);
      float4 q2 = *(const float4*)(hp + 32);
      float4 q3 = *(const float4*)(hp + 36);
      split_frag(q0, q1, Ah[0], Al[0]);
      split_frag(q2, q3, Ah[1], Al[1]);
      int nbq[4];
#pragma unroll
      for (int r = 0; r < 4; ++r) nbq[r] = nbS[quad * 4 + r][t + 1];
#pragma unroll
      for (int g = 0; g < 4; ++g)
#pragma unroll
        for (int r = 0; r < 4; ++r) {
          float v = 0.f;
          if (nbq[r] >= 0) v = y[(size_t)nbq[r] * 256 + g * 64 + w * 16 + n];
          yv[g][r] = v;
        }
    }
  }
#pragma unroll
  for (int r = 0; r < 4; ++r)
    agg[(size_t)(n0 + quad * 4 + r) * HD + w * 16 + n] = h[r];
}

// ---------------- hetero mean + SAGE linear + residual + relu, both sides ----------------
// grid = (625, 2); blockIdx.y: 0 = source side (et 0 + 3), 1 = target side (et 1 + 2).

__global__ __launch_bounds__(256) void combine_kernel(
    const float* __restrict__ aggBase, const float* __restrict__ WlL,
    const float* __restrict__ blL, const float* __restrict__ WrL,
    const float* __restrict__ xS, const float* __restrict__ xT, int has_res,
    float* __restrict__ outS, float* __restrict__ outT) {
  __shared__ __align__(16) float4 tS[3][16][16];
  __shared__ __align__(16) float pS[4][16][64];
  int side = blockIdx.y;
  int etA = side ? 1 : 0, etB = side ? 2 : 3;
  const float* aggA = aggBase + (size_t)etA * N_NODES * HD;
  const float* aggB = aggBase + (size_t)etB * N_NODES * HD;
  const float* WlA = WlL + etA * 4096;
  const float* WlB = WlL + etB * 4096;
  const float* WrA = WrL + etA * 4096;
  const float* WrB = WrL + etB * 4096;
  const float* blA = blL + etA * 64;
  const float* blB = blL + etB * 64;
  const float* xin = side ? xT : xS;
  float* out = side ? outT : outS;
  int tid = threadIdx.x, w = tid >> 6, l = tid & 63;
  int n0 = blockIdx.x * 16;
  {
    const float4* A4 = (const float4*)(aggA + (size_t)n0 * 64);
    const float4* B4 = (const float4*)(aggB + (size_t)n0 * 64);
    const float4* X4 = (const float4*)(xin + (size_t)n0 * 64);
    tS[0][tid >> 4][tid & 15] = A4[tid];
    tS[1][tid >> 4][tid & 15] = B4[tid];
    tS[2][tid >> 4][tid & 15] = X4[tid];
  }
  __syncthreads();
  const float* Wsel = (w == 0) ? WlA : (w == 1) ? WlB : (w == 2) ? WrA : WrB;
  const float4 (*tp)[16] = tS[(w == 0) ? 0 : (w == 1) ? 1 : 2];
  float4 wr[16];
  const float4* W4 = (const float4*)(Wsel + l * 64);
#pragma unroll
  for (int kk = 0; kk < 16; ++kk) wr[kk] = W4[kk];
  for (int m0 = 0; m0 < 16; m0 += 4) {
    float a0 = 0.f, a1 = 0.f, a2 = 0.f, a3 = 0.f;
#pragma unroll
    for (int kk = 0; kk < 16; ++kk) {
      float4 wv = wr[kk];
      a0 = fma4(wv, tp[m0 + 0][kk], a0);
      a1 = fma4(wv, tp[m0 + 1][kk], a1);
      a2 = fma4(wv, tp[m0 + 2][kk], a2);
      a3 = fma4(wv, tp[m0 + 3][kk], a3);
    }
    pS[w][m0 + 0][l] = a0;
    pS[w][m0 + 1][l] = a1;
    pS[w][m0 + 2][l] = a2;
    pS[w][m0 + 3][l] = a3;
  }
  __syncthreads();
  int idx4 = tid * 4;
  int m = idx4 >> 6, l0 = idx4 & 63;
  float4 p0 = *(float4*)&pS[0][m][l0];
  float4 p1 = *(float4*)&pS[1][m][l0];
  float4 p2 = *(float4*)&pS[2][m][l0];
  float4 p3 = *(float4*)&pS[3][m][l0];
  float4 ba = *(const float4*)(blA + l0);
  float4 bb = *(const float4*)(blB + l0);
  float4 r = tS[2][m][l0 >> 2];
  float4 v;
  v.x = 0.5f * (p0.x + p1.x + p2.x + p3.x + ba.x + bb.x) + (has_res ? r.x : 0.f);
  v.y = 0.5f * (p0.y + p1.y + p2.y + p3.y + ba.y + bb.y) + (has_res ? r.y : 0.f);
  v.z = 0.5f * (p0.z + p1.z + p2.z + p3.z + ba.z + bb.z) + (has_res ? r.z : 0.f);
  v.w = 0.5f * (p0.w + p1.w + p2.w + p3.w + ba.w + bb.w) + (has_res ? r.w : 0.f);
  v.x = fmaxf(v.x, 0.f); v.y = fmaxf(v.y, 0.f);
  v.z = fmaxf(v.z, 0.f); v.w = fmaxf(v.w, 0.f);
  ((float4*)(out + (size_t)n0 * 64))[tid] = v;
}

// ---------------- edge head ----------------

__global__ __launch_bounds__(256) void edge_head_kernel(
    const int* __restrict__ esrc, const int* __restrict__ edst, const float* __restrict__ ea,
    const float* __restrict__ s3, const float* __restrict__ t3,
    const float* __restrict__ Wg1, const float* __restrict__ bg1,
    const float* __restrict__ Wg2, const float* __restrict__ bg2,
    const float* __restrict__ Wm1, const float* __restrict__ bm1,
    const float* __restrict__ Wm2, const float* __restrict__ bm2,
    const float* __restrict__ Wm3, const float* __restrict__ bm3,
    float* __restrict__ out) {
  __shared__ __align__(16) float4 xS[64][32];
  __shared__ __align__(16) float4 eaS[64][4];
  int tid = threadIdx.x, w = tid >> 6, l = tid & 63;
  int e0 = blockIdx.x * 64;
  for (int idx = tid; idx < 2048; idx += 256) {
    int e = idx >> 5, kk = idx & 31;
    float4 v;
    if (kk < 16) v = ((const float4*)(s3 + (size_t)esrc[e0 + e] * 64))[kk];
    else         v = ((const float4*)(t3 + (size_t)edst[e0 + e] * 64))[kk - 16];
    xS[e][kk] = v;
  }
  {
    int e = tid >> 2, kk = tid & 3;
    eaS[e][kk] = ((const float4*)(ea + (size_t)(e0 + e) * 16))[kk];
  }
  __syncthreads();
  {
    float4 wr[32];
    const float4* W4 = (const float4*)(Wg1 + l * 128);
#pragma unroll
    for (int kk = 0; kk < 32; ++kk) wr[kk] = W4[kk];
    float bg = bg1[l], w2 = Wg2[l], b2 = bg2[0];
    for (int m0 = 0; m0 < 16; m0 += 4) {
      int e = w * 16 + m0;
      float a0 = bg, a1 = bg, a2 = bg, a3 = bg;
#pragma unroll
      for (int kk = 0; kk < 32; ++kk) {
        float4 wv = wr[kk];
        a0 = fma4(wv, xS[e + 0][kk], a0);
        a1 = fma4(wv, xS[e + 1][kk], a1);
        a2 = fma4(wv, xS[e + 2][kk], a2);
        a3 = fma4(wv, xS[e + 3][kk], a3);
      }
      a0 = fmaxf(a0, 0.f) * w2; a1 = fmaxf(a1, 0.f) * w2;
      a2 = fmaxf(a2, 0.f) * w2; a3 = fmaxf(a3, 0.f) * w2;
#pragma unroll
      for (int off = 32; off; off >>= 1) {
        a0 += __shfl_xor(a0, off); a1 += __shfl_xor(a1, off);
        a2 += __shfl_xor(a2, off); a3 += __shfl_xor(a3, off);
      }
      float g0 = sigmoidf_(a0 + b2), g1 = sigmoidf_(a1 + b2);
      float g2 = sigmoidf_(a2 + b2), g3 = sigmoidf_(a3 + b2);
      float* r0 = (float*)xS[e + 0]; float* r1 = (float*)xS[e + 1];
      float* r2 = (float*)xS[e + 2]; float* r3 = (float*)xS[e + 3];
      r0[l] = fmaf(g0, r0[l] - r0[64 + l], r0[64 + l]);
      r1[l] = fmaf(g1, r1[l] - r1[64 + l], r1[64 + l]);
      r2[l] = fmaf(g2, r2[l] - r2[64 + l], r2[64 + l]);
      r3[l] = fmaf(g3, r3[l] - r3[64 + l], r3[64 + l]);
    }
  }
  __syncthreads();
  {
    float4 wr[20];
    const float4* W4 = (const float4*)(Wm1 + l * 80);
#pragma unroll
    for (int kk = 0; kk < 20; ++kk) wr[kk] = W4[kk];
    float bm = bm1[l];
    float h2v[16];
    for (int m0 = 0; m0 < 16; m0 += 4) {
      int e = w * 16 + m0;
      float a0 = bm, a1 = bm, a2 = bm, a3 = bm;
#pragma unroll
      for (int kk = 0; kk < 16; ++kk) {
        float4 wv = wr[kk];
        a0 = fma4(wv, xS[e + 0][kk], a0);
        a1 = fma4(wv, xS[e + 1][kk], a1);
        a2 = fma4(wv, xS[e + 2][kk], a2);
        a3 = fma4(wv, xS[e + 3][kk], a3);
      }
#pragma unroll
      for (int kk = 0; kk < 4; ++kk) {
        float4 wv = wr[16 + kk];
        a0 = fma4(wv, eaS[e + 0][kk], a0);
        a1 = fma4(wv, eaS[e + 1][kk], a1);
        a2 = fma4(wv, eaS[e + 2][kk], a2);
        a3 = fma4(wv, eaS[e + 3][kk], a3);
      }
      h2v[m0 + 0] = fmaxf(a0, 0.f); h2v[m0 + 1] = fmaxf(a1, 0.f);
      h2v[m0 + 2] = fmaxf(a2, 0.f); h2v[m0 + 3] = fmaxf(a3, 0.f);
    }
#pragma unroll
    for (int m = 0; m < 16; ++m) ((float*)xS[w * 16 + m])[64 + l] = h2v[m];
  }
  __syncthreads();
  {
    int half = l >> 5, j = l & 31;
    float4 wr[16];
    const float4* W4 = (const float4*)(Wm2 + j * 64);
#pragma unroll
    for (int kk = 0; kk < 16; ++kk) wr[kk] = W4[kk];
    float bm = bm2[j], w3a = Wm3[j], w3b = Wm3[32 + j];
    float b3a = bm3[0], b3b = bm3[1];
    for (int mg = 0; mg < 16; mg += 2) {
      int m = mg + half, e = w * 16 + m;
      float acc = bm;
#pragma unroll
      for (int kk = 0; kk < 16; ++kk) acc = fma4(wr[kk], xS[e][16 + kk], acc);
      float h3 = fmaxf(acc, 0.f);
      float p0 = h3 * w3a, p1 = h3 * w3b;
#pragma unroll
      for (int off = 16; off; off >>= 1) {
        p0 += __shfl_xor(p0, off);
        p1 += __shfl_xor(p1, off);
      }
      if (j == 0) {
        int ge = e0 + e;
        out[ge * 2 + 0] = p0 + b3a;
        out[ge * 2 + 1] = p1 + b3b;
      }
    }
  }
}

// ---------------- host orchestration ----------------

extern "C" void kernel_launch(void* const* d_in, const int* in_sizes, int n_in, void* d_out,
                              int out_size, void* d_ws, size_t ws_size, hipStream_t stream) {
  const float* x_source = (const float*)d_in[0];
  const float* x_target = (const float*)d_in[1];
  const int* edges = (const int*)d_in[2];
  const float* edge_attr = (const float*)d_in[3];
  const float* We_s1 = (const float*)d_in[4];
  const float* be_s1 = (const float*)d_in[5];
  const float* We_s2 = (const float*)d_in[6];
  const float* be_s2 = (const float*)d_in[7];
  const float* We_t1 = (const float*)d_in[8];
  const float* be_t1 = (const float*)d_in[9];
  const float* We_t2 = (const float*)d_in[10];
  const float* be_t2 = (const float*)d_in[11];
  const float* Wih = (const float*)d_in[12];
  const float* Whh = (const float*)d_in[13];
  const float* bih = (const float*)d_in[14];
  const float* bhh = (const float*)d_in[15];
  const float* Wl = (const float*)d_in[16];
  const float* bl = (const float*)d_in[17];
  const float* Wr = (const float*)d_in[18];
  const float* Wg1 = (const float*)d_in[19];
  const float* bg1 = (const float*)d_in[20];
  const float* Wg2 = (const float*)d_in[21];
  const float* bg2 = (const float*)d_in[22];
  const float* Wm1 = (const float*)d_in[23];
  const float* bm1 = (const float*)d_in[24];
  const float* Wm2 = (const float*)d_in[25];
  const float* bm2 = (const float*)d_in[26];
  const float* Wm3 = (const float*)d_in[27];
  const float* bm3 = (const float*)d_in[28];
  float* out = (float*)d_out;

  int* nbr = (int*)d_ws;                       // 4*N*12
  int* cnt = nbr + 4 * N_NODES * MAXD;         // 4*N
  int* pool = cnt + 4 * N_NODES;               // 4*N*CAP
  float* fb = (float*)(pool + 4 * N_NODES * CAP);
  float* bufS[2] = {fb, fb + N_NODES * HD};
  float* bufT[2] = {fb + 2 * N_NODES * HD, fb + 3 * N_NODES * HD};
  float* aggBase = fb + (size_t)4 * N_NODES * HD;        // 4 * N*64
  float* y4 = fb + (size_t)8 * N_NODES * HD;             // 4 * N*256
  short* whh16 = (short*)(y4 + (size_t)4 * N_NODES * 256);  // 12 * 32768 shorts

  hipMemsetAsync(cnt, 0, 4 * N_NODES * sizeof(int), stream);
  prep_whh_kernel<<<96, 256, 0, stream>>>(Whh, whh16);
  scatter_kernel<<<(4 * N_EDGES + 255) / 256, 256, 0, stream>>>(edges, cnt, pool);
  sortrows_kernel<<<(4 * N_NODES + 63) / 64, 64, 0, stream>>>(cnt, pool, nbr);
  encode_kernel<32><<<N_NODES / 4, 256, 0, stream>>>(x_source, We_s1, be_s1, We_s2, be_s2, bufS[0]);
  encode_kernel<24><<<N_NODES / 4, 256, 0, stream>>>(x_target, We_t1, be_t1, We_t2, be_t2, bufT[0]);

  int cur = 0;
  for (int L = 0; L < 3; ++L) {
    ygemm_kernel<<<dim3(N_NODES / 16, 4), 256, 0, stream>>>(bufS[cur], bufT[cur],
        Wih + (size_t)L * 4 * 16384, y4);
    lstm_mfma_kernel<<<dim3(N_NODES / 16, 4), 256, 0, stream>>>(nbr, y4,
        whh16 + (size_t)L * 4 * 32768, bih + L * 1024, bhh + L * 1024, aggBase);
    combine_kernel<<<dim3(N_NODES / 16, 2), 256, 0, stream>>>(aggBase,
        Wl + (size_t)L * 4 * 4096, bl + L * 256, Wr + (size_t)L * 4 * 4096,
        bufS[cur], bufT[cur], L > 0 ? 1 : 0, bufS[1 - cur], bufT[1 - cur]);
    cur = 1 - cur;
  }

  edge_head_kernel<<<N_EDGES / 64, 256, 0, stream>>>(edges + 4 * N_EDGES, edges + 5 * N_EDGES,
      edge_attr, bufS[cur], bufT[cur], Wg1, bg1, Wg2, bg2, Wm1, bm1, Wm2, bm2, Wm3, bm3, out);
}

// Round 5
// 746.884 us; speedup vs baseline: 3.4460x; 1.0690x over previous
//
#include <hip/hip_runtime.h>

#define N_NODES 10000
#define N_EDGES 40000
#define HD 64
#define MAXD 12
#define CAP 32
#define YROW ((size_t)(N_NODES + 1) * 256)  // per-edge-type y stride, +1 dummy zero row

typedef __attribute__((ext_vector_type(8))) short short8;
typedef __attribute__((ext_vector_type(4))) float floatx4;

__device__ __forceinline__ float sigmoidf_(float x) {
  return 1.0f / (1.0f + __expf(-x));
}
__device__ __forceinline__ float tanhf_(float x) {
  float ax = fabsf(x);
  float t = __expf(-2.0f * ax);
  float r = (1.0f - t) / (1.0f + t);
  return copysignf(r, x);
}
__device__ __forceinline__ float fma4(float4 w, float4 x, float a) {
  a = fmaf(w.x, x.x, a);
  a = fmaf(w.y, x.y, a);
  a = fmaf(w.z, x.z, a);
  return fmaf(w.w, x.w, a);
}

// split 8 consecutive fp32 into bf16 hi/lo fragments (used by weight prep only)
__device__ __forceinline__ void split_frag(float4 a, float4 b, short8& hi, short8& lo) {
  float f[8] = {a.x, a.y, a.z, a.w, b.x, b.y, b.z, b.w};
  union { short8 v; unsigned d[4]; } H, L;
#pragma unroll
  for (int p = 0; p < 4; ++p) {
    unsigned u0 = __float_as_uint(f[2 * p]);
    unsigned u1 = __float_as_uint(f[2 * p + 1]);
    H.d[p] = (u0 >> 16) | (u1 & 0xFFFF0000u);
    float l0 = f[2 * p] - __uint_as_float(u0 & 0xFFFF0000u);
    float l1 = f[2 * p + 1] - __uint_as_float(u1 & 0xFFFF0000u);
    L.d[p] = (__float_as_uint(l0) >> 16) | (__float_as_uint(l1) & 0xFFFF0000u);
  }
  hi = H.v;
  lo = L.v;
}

// ---------------- adjacency build ----------------

__global__ void scatter_kernel(const int* __restrict__ edges, int* __restrict__ cnt,
                               int* __restrict__ pool) {
  int idx = blockIdx.x * 256 + threadIdx.x;
  if (idx >= 4 * N_EDGES) return;
  int et = idx / N_EDGES, e = idx - et * N_EDGES;
  int src = edges[(et * 2) * N_EDGES + e];
  int dst = edges[(et * 2 + 1) * N_EDGES + e];
  int slot = atomicAdd(&cnt[et * N_NODES + dst], 1);
  if (slot < CAP) pool[(et * N_NODES + dst) * CAP + slot] = src;
}

__global__ void sortrows_kernel(const int* __restrict__ cnt, const int* __restrict__ pool,
                                int* __restrict__ nbr) {
  __shared__ int buf[64][CAP + 1];
  int idx = blockIdx.x * 64 + threadIdx.x;
  if (idx >= 4 * N_NODES) return;
  int n = idx % N_NODES;
  int c = cnt[idx];
  if (c > CAP) c = CAP;
  int* a = buf[threadIdx.x];
  const int* row = pool + idx * CAP;
  for (int j = 0; j < c; ++j) a[j] = row[j] * 2;
  a[c] = n * 2 + 1;  // self loop sorts after equal-src originals (stable argsort semantics)
  ++c;
  for (int i2 = 1; i2 < c; ++i2) {
    int key = a[i2];
    int b = i2 - 1;
    while (b >= 0 && a[b] > key) { a[b + 1] = a[b]; --b; }
    a[b + 1] = key;
  }
  int* onbr = nbr + idx * MAXD;
  // pad with dummy node N_NODES (zero y row) -> no predication in lstm gather
  for (int t = 0; t < MAXD; ++t) onbr[t] = (t < c) ? (a[t] >> 1) : N_NODES;
}

__global__ void zero_dummy_kernel(float* __restrict__ ybase) {
  int tid = threadIdx.x;
#pragma unroll
  for (int et = 0; et < 4; ++et)
    ybase[(size_t)et * YROW + (size_t)N_NODES * 256 + tid] = 0.0f;
}

// ---------------- Whh -> fragment-ordered bf16 hi/lo ----------------

__global__ __launch_bounds__(256) void prep_whh_kernel(const float* __restrict__ Whh,
                                                       short* __restrict__ whh16) {
  int gid = blockIdx.x * 256 + threadIdx.x;
  if (gid >= 384 * 64) return;
  int lane = gid & 63;
  int combo = gid >> 6;
  int kc = combo & 1;
  int g = (combo >> 1) & 3;
  int w = (combo >> 3) & 3;
  int i = combo >> 5;
  int gate = g * 64 + w * 16 + (lane & 15);
  int k0 = kc * 32 + (lane >> 4) * 8;
  const float* src = Whh + ((size_t)i * 256 + gate) * 64 + k0;
  float4 a = ((const float4*)src)[0];
  float4 b = ((const float4*)src)[1];
  short8 hi, lo;
  split_frag(a, b, hi, lo);
  short8* dst = (short8*)whh16;
  dst[(combo * 2 + 0) * 64 + lane] = hi;
  dst[(combo * 2 + 1) * 64 + lane] = lo;
}

// ---------------- node encoders ----------------

template <int IN>
__global__ __launch_bounds__(256) void encode_kernel(const float* __restrict__ x,
    const float* __restrict__ W1, const float* __restrict__ b1,
    const float* __restrict__ W2, const float* __restrict__ b2, float* __restrict__ out) {
  __shared__ float xs[4][IN];
  __shared__ float h1[4][HD];
  int w = threadIdx.x >> 6, l = threadIdx.x & 63;
  int n = blockIdx.x * 4 + w;
  if (l < IN) xs[w][l] = x[n * IN + l];
  __syncthreads();
  float acc = b1[l];
#pragma unroll
  for (int k = 0; k < IN; ++k) acc = fmaf(xs[w][k], W1[l * IN + k], acc);
  h1[w][l] = fmaxf(acc, 0.0f);
  __syncthreads();
  float acc2 = b2[l];
#pragma unroll
  for (int k = 0; k < HD; ++k) acc2 = fmaf(h1[w][k], W2[l * HD + k], acc2);
  out[n * HD + l] = acc2;
}

// ---------------- y = x_src @ Wih.T ; output layout [node][u*4 + g] ----------------

__global__ __launch_bounds__(256) void ygemm_kernel(const float* __restrict__ xs0,
    const float* __restrict__ xt0, const float* __restrict__ WihL, float* __restrict__ ybase) {
  __shared__ __align__(16) float xs[16][HD];
  __shared__ __align__(16) float pS[16][260];
  int et = blockIdx.y;
  const float* x = (et == 0 || et == 2) ? xs0 : xt0;
  const float* Wih = WihL + (size_t)et * 16384;
  float* y = ybase + (size_t)et * YROW;
  int tid = threadIdx.x, w = tid >> 6, l = tid & 63;
  int n0 = blockIdx.x * 16;
  for (int r = tid; r < 16 * HD; r += 256) xs[r >> 6][r & 63] = x[n0 * HD + r];
  __syncthreads();
  int j = w * 64 + l;
  float4 wr[16];
  const float4* W4 = (const float4*)(Wih + j * HD);
#pragma unroll
  for (int kk = 0; kk < 16; ++kk) wr[kk] = W4[kk];
  for (int m = 0; m < 16; ++m) {
    float acc = 0.0f;
    const float4* xv4 = (const float4*)xs[m];
    float acc2 = 0.0f;
#pragma unroll
    for (int kk = 0; kk < 16; kk += 2) {
      float4 xv = xv4[kk], wv = wr[kk];
      acc = fmaf(wv.x, xv.x, acc); acc = fmaf(wv.y, xv.y, acc);
      acc = fmaf(wv.z, xv.z, acc); acc = fmaf(wv.w, xv.w, acc);
      float4 xv2 = xv4[kk + 1], wv2 = wr[kk + 1];
      acc2 = fmaf(wv2.x, xv2.x, acc2); acc2 = fmaf(wv2.y, xv2.y, acc2);
      acc2 = fmaf(wv2.z, xv2.z, acc2); acc2 = fmaf(wv2.w, xv2.w, acc2);
    }
    pS[m][l * 4 + w] = acc + acc2;  // unit u = l, gate g = w -> [u*4+g]
  }
  __syncthreads();
#pragma unroll
  for (int cc = 0; cc < 4; ++cc) {
    int g4 = cc * 256 + tid;
    int node = g4 >> 6, col = g4 & 63;
    float4 v = *(const float4*)&pS[node][col * 4];
    ((float4*)(y + (size_t)(n0 + node) * 256))[col] = v;
  }
}

// ---------------- SAGE-LSTM aggregation, MFMA split-bf16, 4 edge types ----------------
// grid = (625, 4). Block = 16 nodes, 4 waves; wave w owns units [16w,16w+16)
// for all 4 gates (i,f,g,o land in one lane's acc regs). h is exchanged via LDS
// as writer-split packed u32 (hi-bf16 | lo-bf16); readers unpack with v_perm.

__global__ __launch_bounds__(256) void lstm_mfma_kernel(const int* __restrict__ nbrAll,
    const float* __restrict__ ybase, const short* __restrict__ whh16L,
    const float* __restrict__ bihL, const float* __restrict__ bhhL, float* __restrict__ aggBase) {
  __shared__ __align__(16) unsigned pkS[2][16 * 68];  // [node][u], stride 68 -> 2-way (free)
  __shared__ int nbS[16][MAXD];
  int et = blockIdx.y;
  const int* nbr = nbrAll + (size_t)et * N_NODES * MAXD;
  const float4* y4 = (const float4*)(ybase + (size_t)et * YROW);
  const short* whh16 = whh16L + (size_t)et * 32768;
  const float* bih = bihL + et * 256;
  const float* bhh = bhhL + et * 256;
  float* agg = aggBase + (size_t)et * N_NODES * HD;
  int tid = threadIdx.x, w = tid >> 6, l = tid & 63;
  int quad = l >> 4, n = l & 15, u = w * 16 + n;
  int n0 = blockIdx.x * 16;
  if (tid < 16 * MAXD) ((int*)nbS)[tid] = nbr[n0 * MAXD + tid];
  short8 Bh[4][2], Bl[4][2];
  {
    const short8* wf = (const short8*)whh16;
#pragma unroll
    for (int g = 0; g < 4; ++g)
#pragma unroll
      for (int kc = 0; kc < 2; ++kc) {
        int combo = (w * 4 + g) * 2 + kc;
        Bh[g][kc] = wf[(combo * 2 + 0) * 64 + l];
        Bl[g][kc] = wf[(combo * 2 + 1) * 64 + l];
      }
  }
  float bs[4];
#pragma unroll
  for (int g = 0; g < 4; ++g) bs[g] = bih[g * 64 + u] + bhh[g * 64 + u];
  float c[4] = {0.f, 0.f, 0.f, 0.f}, h[4];
  short8 Ah[2], Al[2];
#pragma unroll
  for (int kc = 0; kc < 2; ++kc) { Ah[kc] = (short8)0; Al[kc] = (short8)0; }
  __syncthreads();
  float4 Y[4];
#pragma unroll
  for (int r = 0; r < 4; ++r) Y[r] = y4[(size_t)nbS[quad * 4 + r][0] * 64 + u];
  for (int t = 0; t < MAXD; ++t) {
    float yg[4][4];
#pragma unroll
    for (int r = 0; r < 4; ++r) {
      yg[0][r] = Y[r].x; yg[1][r] = Y[r].y; yg[2][r] = Y[r].z; yg[3][r] = Y[r].w;
    }
    floatx4 acc[4];
#pragma unroll
    for (int g = 0; g < 4; ++g) {
      floatx4 a = {yg[g][0], yg[g][1], yg[g][2], yg[g][3]};
      a = __builtin_amdgcn_mfma_f32_16x16x32_bf16(Ah[0], Bh[g][0], a, 0, 0, 0);
      a = __builtin_amdgcn_mfma_f32_16x16x32_bf16(Ah[1], Bh[g][1], a, 0, 0, 0);
      a = __builtin_amdgcn_mfma_f32_16x16x32_bf16(Al[0], Bh[g][0], a, 0, 0, 0);
      a = __builtin_amdgcn_mfma_f32_16x16x32_bf16(Al[1], Bh[g][1], a, 0, 0, 0);
      a = __builtin_amdgcn_mfma_f32_16x16x32_bf16(Ah[0], Bl[g][0], a, 0, 0, 0);
      a = __builtin_amdgcn_mfma_f32_16x16x32_bf16(Ah[1], Bl[g][1], a, 0, 0, 0);
      acc[g] = a;
    }
    if (t + 1 < MAXD) {  // prefetch next y; latency hidden under gate math
#pragma unroll
      for (int r = 0; r < 4; ++r) Y[r] = y4[(size_t)nbS[quad * 4 + r][t + 1] * 64 + u];
    }
    int buf = (t + 1) & 1;
#pragma unroll
    for (int r = 0; r < 4; ++r) {
      float gi = acc[0][r] + bs[0];
      float gf = acc[1][r] + bs[1];
      float gg = acc[2][r] + bs[2];
      float go = acc[3][r] + bs[3];
      c[r] = fmaf(sigmoidf_(gf), c[r], sigmoidf_(gi) * tanhf_(gg));
      h[r] = sigmoidf_(go) * tanhf_(c[r]);
      unsigned ub = __float_as_uint(h[r]);
      float lo = h[r] - __uint_as_float(ub & 0xFFFF0000u);
      pkS[buf][(quad * 4 + r) * 68 + u] =
          __builtin_amdgcn_perm(ub, __float_as_uint(lo), 0x07060302u);
    }
    __syncthreads();
    if (t + 1 < MAXD) {
#pragma unroll
      for (int kc = 0; kc < 2; ++kc) {
        const unsigned* pb = &pkS[buf][n * 68 + kc * 32 + quad * 8];
        uint4 qa = *(const uint4*)pb;
        uint4 qb = *(const uint4*)(pb + 4);
        union { short8 s; unsigned d[4]; } H, L;
        H.d[0] = __builtin_amdgcn_perm(qa.y, qa.x, 0x07060302u);
        H.d[1] = __builtin_amdgcn_perm(qa.w, qa.z, 0x07060302u);
        H.d[2] = __builtin_amdgcn_perm(qb.y, qb.x, 0x07060302u);
        H.d[3] = __builtin_amdgcn_perm(qb.w, qb.z, 0x07060302u);
        L.d[0] = __builtin_amdgcn_perm(qa.y, qa.x, 0x05040100u);
        L.d[1] = __builtin_amdgcn_perm(qa.w, qa.z, 0x05040100u);
        L.d[2] = __builtin_amdgcn_perm(qb.y, qb.x, 0x05040100u);
        L.d[3] = __builtin_amdgcn_perm(qb.w, qb.z, 0x05040100u);
        Ah[kc] = H.s;
        Al[kc] = L.s;
      }
    }
  }
#pragma unroll
  for (int r = 0; r < 4; ++r)
    agg[(size_t)(n0 + quad * 4 + r) * HD + u] = h[r];
}

// ---------------- hetero mean + SAGE linear + residual + relu, both sides ----------------

__global__ __launch_bounds__(256) void combine_kernel(
    const float* __restrict__ aggBase, const float* __restrict__ WlL,
    const float* __restrict__ blL, const float* __restrict__ WrL,
    const float* __restrict__ xS, const float* __restrict__ xT, int has_res,
    float* __restrict__ outS, float* __restrict__ outT) {
  __shared__ __align__(16) float4 tS[3][16][16];
  __shared__ __align__(16) float pS[4][16][64];
  int side = blockIdx.y;
  int etA = side ? 1 : 0, etB = side ? 2 : 3;
  const float* aggA = aggBase + (size_t)etA * N_NODES * HD;
  const float* aggB = aggBase + (size_t)etB * N_NODES * HD;
  const float* WlA = WlL + etA * 4096;
  const float* WlB = WlL + etB * 4096;
  const float* WrA = WrL + etA * 4096;
  const float* WrB = WrL + etB * 4096;
  const float* blA = blL + etA * 64;
  const float* blB = blL + etB * 64;
  const float* xin = side ? xT : xS;
  float* out = side ? outT : outS;
  int tid = threadIdx.x, w = tid >> 6, l = tid & 63;
  int n0 = blockIdx.x * 16;
  {
    const float4* A4 = (const float4*)(aggA + (size_t)n0 * 64);
    const float4* B4 = (const float4*)(aggB + (size_t)n0 * 64);
    const float4* X4 = (const float4*)(xin + (size_t)n0 * 64);
    tS[0][tid >> 4][tid & 15] = A4[tid];
    tS[1][tid >> 4][tid & 15] = B4[tid];
    tS[2][tid >> 4][tid & 15] = X4[tid];
  }
  __syncthreads();
  const float* Wsel = (w == 0) ? WlA : (w == 1) ? WlB : (w == 2) ? WrA : WrB;
  const float4 (*tp)[16] = tS[(w == 0) ? 0 : (w == 1) ? 1 : 2];
  float4 wr[16];
  const float4* W4 = (const float4*)(Wsel + l * 64);
#pragma unroll
  for (int kk = 0; kk < 16; ++kk) wr[kk] = W4[kk];
  for (int m0 = 0; m0 < 16; m0 += 4) {
    float a0 = 0.f, a1 = 0.f, a2 = 0.f, a3 = 0.f;
#pragma unroll
    for (int kk = 0; kk < 16; ++kk) {
      float4 wv = wr[kk];
      a0 = fma4(wv, tp[m0 + 0][kk], a0);
      a1 = fma4(wv, tp[m0 + 1][kk], a1);
      a2 = fma4(wv, tp[m0 + 2][kk], a2);
      a3 = fma4(wv, tp[m0 + 3][kk], a3);
    }
    pS[w][m0 + 0][l] = a0;
    pS[w][m0 + 1][l] = a1;
    pS[w][m0 + 2][l] = a2;
    pS[w][m0 + 3][l] = a3;
  }
  __syncthreads();
  int idx4 = tid * 4;
  int m = idx4 >> 6, l0 = idx4 & 63;
  float4 p0 = *(float4*)&pS[0][m][l0];
  float4 p1 = *(float4*)&pS[1][m][l0];
  float4 p2 = *(float4*)&pS[2][m][l0];
  float4 p3 = *(float4*)&pS[3][m][l0];
  float4 ba = *(const float4*)(blA + l0);
  float4 bb = *(const float4*)(blB + l0);
  float4 r = tS[2][m][l0 >> 2];
  float4 v;
  v.x = 0.5f * (p0.x + p1.x + p2.x + p3.x + ba.x + bb.x) + (has_res ? r.x : 0.f);
  v.y = 0.5f * (p0.y + p1.y + p2.y + p3.y + ba.y + bb.y) + (has_res ? r.y : 0.f);
  v.z = 0.5f * (p0.z + p1.z + p2.z + p3.z + ba.z + bb.z) + (has_res ? r.z : 0.f);
  v.w = 0.5f * (p0.w + p1.w + p2.w + p3.w + ba.w + bb.w) + (has_res ? r.w : 0.f);
  v.x = fmaxf(v.x, 0.f); v.y = fmaxf(v.y, 0.f);
  v.z = fmaxf(v.z, 0.f); v.w = fmaxf(v.w, 0.f);
  ((float4*)(out + (size_t)n0 * 64))[tid] = v;
}

// ---------------- edge head ----------------

__global__ __launch_bounds__(256) void edge_head_kernel(
    const int* __restrict__ esrc, const int* __restrict__ edst, const float* __restrict__ ea,
    const float* __restrict__ s3, const float* __restrict__ t3,
    const float* __restrict__ Wg1, const float* __restrict__ bg1,
    const float* __restrict__ Wg2, const float* __restrict__ bg2,
    const float* __restrict__ Wm1, const float* __restrict__ bm1,
    const float* __restrict__ Wm2, const float* __restrict__ bm2,
    const float* __restrict__ Wm3, const float* __restrict__ bm3,
    float* __restrict__ out) {
  __shared__ __align__(16) float4 xS[64][32];
  __shared__ __align__(16) float4 eaS[64][4];
  int tid = threadIdx.x, w = tid >> 6, l = tid & 63;
  int e0 = blockIdx.x * 64;
  for (int idx = tid; idx < 2048; idx += 256) {
    int e = idx >> 5, kk = idx & 31;
    float4 v;
    if (kk < 16) v = ((const float4*)(s3 + (size_t)esrc[e0 + e] * 64))[kk];
    else         v = ((const float4*)(t3 + (size_t)edst[e0 + e] * 64))[kk - 16];
    xS[e][kk] = v;
  }
  {
    int e = tid >> 2, kk = tid & 3;
    eaS[e][kk] = ((const float4*)(ea + (size_t)(e0 + e) * 16))[kk];
  }
  __syncthreads();
  {
    float4 wr[32];
    const float4* W4 = (const float4*)(Wg1 + l * 128);
#pragma unroll
    for (int kk = 0; kk < 32; ++kk) wr[kk] = W4[kk];
    float bg = bg1[l], w2 = Wg2[l], b2 = bg2[0];
    for (int m0 = 0; m0 < 16; m0 += 4) {
      int e = w * 16 + m0;
      float a0 = bg, a1 = bg, a2 = bg, a3 = bg;
#pragma unroll
      for (int kk = 0; kk < 32; ++kk) {
        float4 wv = wr[kk];
        a0 = fma4(wv, xS[e + 0][kk], a0);
        a1 = fma4(wv, xS[e + 1][kk], a1);
        a2 = fma4(wv, xS[e + 2][kk], a2);
        a3 = fma4(wv, xS[e + 3][kk], a3);
      }
      a0 = fmaxf(a0, 0.f) * w2; a1 = fmaxf(a1, 0.f) * w2;
      a2 = fmaxf(a2, 0.f) * w2; a3 = fmaxf(a3, 0.f) * w2;
#pragma unroll
      for (int off = 32; off; off >>= 1) {
        a0 += __shfl_xor(a0, off); a1 += __shfl_xor(a1, off);
        a2 += __shfl_xor(a2, off); a3 += __shfl_xor(a3, off);
      }
      float g0 = sigmoidf_(a0 + b2), g1 = sigmoidf_(a1 + b2);
      float g2 = sigmoidf_(a2 + b2), g3 = sigmoidf_(a3 + b2);
      float* r0 = (float*)xS[e + 0]; float* r1 = (float*)xS[e + 1];
      float* r2 = (float*)xS[e + 2]; float* r3 = (float*)xS[e + 3];
      r0[l] = fmaf(g0, r0[l] - r0[64 + l], r0[64 + l]);
      r1[l] = fmaf(g1, r1[l] - r1[64 + l], r1[64 + l]);
      r2[l] = fmaf(g2, r2[l] - r2[64 + l], r2[64 + l]);
      r3[l] = fmaf(g3, r3[l] - r3[64 + l], r3[64 + l]);
    }
  }
  __syncthreads();
  {
    float4 wr[20];
    const float4* W4 = (const float4*)(Wm1 + l * 80);
#pragma unroll
    for (int kk = 0; kk < 20; ++kk) wr[kk] = W4[kk];
    float bm = bm1[l];
    float h2v[16];
    for (int m0 = 0; m0 < 16; m0 += 4) {
      int e = w * 16 + m0;
      float a0 = bm, a1 = bm, a2 = bm, a3 = bm;
#pragma unroll
      for (int kk = 0; kk < 16; ++kk) {
        float4 wv = wr[kk];
        a0 = fma4(wv, xS[e + 0][kk], a0);
        a1 = fma4(wv, xS[e + 1][kk], a1);
        a2 = fma4(wv, xS[e + 2][kk], a2);
        a3 = fma4(wv, xS[e + 3][kk], a3);
      }
#pragma unroll
      for (int kk = 0; kk < 4; ++kk) {
        float4 wv = wr[16 + kk];
        a0 = fma4(wv, eaS[e + 0][kk], a0);
        a1 = fma4(wv, eaS[e + 1][kk], a1);
        a2 = fma4(wv, eaS[e + 2][kk], a2);
        a3 = fma4(wv, eaS[e + 3][kk], a3);
      }
      h2v[m0 + 0] = fmaxf(a0, 0.f); h2v[m0 + 1] = fmaxf(a1, 0.f);
      h2v[m0 + 2] = fmaxf(a2, 0.f); h2v[m0 + 3] = fmaxf(a3, 0.f);
    }
#pragma unroll
    for (int m = 0; m < 16; ++m) ((float*)xS[w * 16 + m])[64 + l] = h2v[m];
  }
  __syncthreads();
  {
    int half = l >> 5, j = l & 31;
    float4 wr[16];
    const float4* W4 = (const float4*)(Wm2 + j * 64);
#pragma unroll
    for (int kk = 0; kk < 16; ++kk) wr[kk] = W4[kk];
    float bm = bm2[j], w3a = Wm3[j], w3b = Wm3[32 + j];
    float b3a = bm3[0], b3b = bm3[1];
    for (int mg = 0; mg < 16; mg += 2) {
      int m = mg + half, e = w * 16 + m;
      float acc = bm;
#pragma unroll
      for (int kk = 0; kk < 16; ++kk) acc = fma4(wr[kk], xS[e][16 + kk], acc);
      float h3 = fmaxf(acc, 0.f);
      float p0 = h3 * w3a, p1 = h3 * w3b;
#pragma unroll
      for (int off = 16; off; off >>= 1) {
        p0 += __shfl_xor(p0, off);
        p1 += __shfl_xor(p1, off);
      }
      if (j == 0) {
        int ge = e0 + e;
        out[ge * 2 + 0] = p0 + b3a;
        out[ge * 2 + 1] = p1 + b3b;
      }
    }
  }
}

// ---------------- host orchestration ----------------

extern "C" void kernel_launch(void* const* d_in, const int* in_sizes, int n_in, void* d_out,
                              int out_size, void* d_ws, size_t ws_size, hipStream_t stream) {
  const float* x_source = (const float*)d_in[0];
  const float* x_target = (const float*)d_in[1];
  const int* edges = (const int*)d_in[2];
  const float* edge_attr = (const float*)d_in[3];
  const float* We_s1 = (const float*)d_in[4];
  const float* be_s1 = (const float*)d_in[5];
  const float* We_s2 = (const float*)d_in[6];
  const float* be_s2 = (const float*)d_in[7];
  const float* We_t1 = (const float*)d_in[8];
  const float* be_t1 = (const float*)d_in[9];
  const float* We_t2 = (const float*)d_in[10];
  const float* be_t2 = (const float*)d_in[11];
  const float* Wih = (const float*)d_in[12];
  const float* Whh = (const float*)d_in[13];
  const float* bih = (const float*)d_in[14];
  const float* bhh = (const float*)d_in[15];
  const float* Wl = (const float*)d_in[16];
  const float* bl = (const float*)d_in[17];
  const float* Wr = (const float*)d_in[18];
  const float* Wg1 = (const float*)d_in[19];
  const float* bg1 = (const float*)d_in[20];
  const float* Wg2 = (const float*)d_in[21];
  const float* bg2 = (const float*)d_in[22];
  const float* Wm1 = (const float*)d_in[23];
  const float* bm1 = (const float*)d_in[24];
  const float* Wm2 = (const float*)d_in[25];
  const float* bm2 = (const float*)d_in[26];
  const float* Wm3 = (const float*)d_in[27];
  const float* bm3 = (const float*)d_in[28];
  float* out = (float*)d_out;

  int* nbr = (int*)d_ws;                       // 4*N*12
  int* cnt = nbr + 4 * N_NODES * MAXD;         // 4*N
  int* pool = cnt + 4 * N_NODES;               // 4*N*CAP
  float* fb = (float*)(pool + 4 * N_NODES * CAP);
  float* bufS[2] = {fb, fb + N_NODES * HD};
  float* bufT[2] = {fb + 2 * N_NODES * HD, fb + 3 * N_NODES * HD};
  float* aggBase = fb + (size_t)4 * N_NODES * HD;        // 4 * N*64
  float* y4 = fb + (size_t)8 * N_NODES * HD;             // 4 * (N+1)*256
  short* whh16 = (short*)(y4 + 4 * YROW);                // 12 * 32768 shorts

  hipMemsetAsync(cnt, 0, 4 * N_NODES * sizeof(int), stream);
  prep_whh_kernel<<<96, 256, 0, stream>>>(Whh, whh16);
  zero_dummy_kernel<<<1, 256, 0, stream>>>(y4);
  scatter_kernel<<<(4 * N_EDGES + 255) / 256, 256, 0, stream>>>(edges, cnt, pool);
  sortrows_kernel<<<(4 * N_NODES + 63) / 64, 64, 0, stream>>>(cnt, pool, nbr);
  encode_kernel<32><<<N_NODES / 4, 256, 0, stream>>>(x_source, We_s1, be_s1, We_s2, be_s2, bufS[0]);
  encode_kernel<24><<<N_NODES / 4, 256, 0, stream>>>(x_target, We_t1, be_t1, We_t2, be_t2, bufT[0]);

  int cur = 0;
  for (int L = 0; L < 3; ++L) {
    ygemm_kernel<<<dim3(N_NODES / 16, 4), 256, 0, stream>>>(bufS[cur], bufT[cur],
        Wih + (size_t)L * 4 * 16384, y4);
    lstm_mfma_kernel<<<dim3(N_NODES / 16, 4), 256, 0, stream>>>(nbr, y4,
        whh16 + (size_t)L * 4 * 32768, bih + L * 1024, bhh + L * 1024, aggBase);
    combine_kernel<<<dim3(N_NODES / 16, 2), 256, 0, stream>>>(aggBase,
        Wl + (size_t)L * 4 * 4096, bl + L * 256, Wr + (size_t)L * 4 * 4096,
        bufS[cur], bufT[cur], L > 0 ? 1 : 0, bufS[1 - cur], bufT[1 - cur]);
    cur = 1 - cur;
  }

  edge_head_kernel<<<N_EDGES / 64, 256, 0, stream>>>(edges + 4 * N_EDGES, edges + 5 * N_EDGES,
      edge_attr, bufS[cur], bufT[cur], Wg1, bg1, Wg2, bg2, Wm1, bm1, Wm2, bm2, Wm3, bm3, out);
}

// Round 6
// 489.385 us; speedup vs baseline: 5.2591x; 1.5262x over previous
//
#include <hip/hip_runtime.h>

#define N_NODES 10000
#define N_EDGES 40000
#define HD 64
#define MAXD 12
#define CAP 32
#define YROW ((size_t)(N_NODES + 1) * 256)  // per-edge-type y stride, +1 dummy zero row

typedef __attribute__((ext_vector_type(8))) short short8;
typedef __attribute__((ext_vector_type(4))) float floatx4;

#define MFMA16(A, B, C) __builtin_amdgcn_mfma_f32_16x16x32_bf16(A, B, C, 0, 0, 0)

__device__ __forceinline__ float sigmoidf_(float x) {
  return 1.0f / (1.0f + __expf(-x));
}
__device__ __forceinline__ float fma4(float4 w, float4 x, float a) {
  a = fmaf(w.x, x.x, a);
  a = fmaf(w.y, x.y, a);
  a = fmaf(w.z, x.z, a);
  return fmaf(w.w, x.w, a);
}

// split 8 consecutive fp32 into bf16 hi/lo fragments
__device__ __forceinline__ void split_frag(float4 a, float4 b, short8& hi, short8& lo) {
  float f[8] = {a.x, a.y, a.z, a.w, b.x, b.y, b.z, b.w};
  union { short8 v; unsigned d[4]; } H, L;
#pragma unroll
  for (int p = 0; p < 4; ++p) {
    unsigned u0 = __float_as_uint(f[2 * p]);
    unsigned u1 = __float_as_uint(f[2 * p + 1]);
    H.d[p] = (u0 >> 16) | (u1 & 0xFFFF0000u);
    float l0 = f[2 * p] - __uint_as_float(u0 & 0xFFFF0000u);
    float l1 = f[2 * p + 1] - __uint_as_float(u1 & 0xFFFF0000u);
    L.d[p] = (__float_as_uint(l0) >> 16) | (__float_as_uint(l1) & 0xFFFF0000u);
  }
  hi = H.v;
  lo = L.v;
}

// ---------------- adjacency build ----------------

__global__ void scatter_kernel(const int* __restrict__ edges, int* __restrict__ cnt,
                               int* __restrict__ pool) {
  int idx = blockIdx.x * 256 + threadIdx.x;
  if (idx >= 4 * N_EDGES) return;
  int et = idx / N_EDGES, e = idx - et * N_EDGES;
  int src = edges[(et * 2) * N_EDGES + e];
  int dst = edges[(et * 2 + 1) * N_EDGES + e];
  int slot = atomicAdd(&cnt[et * N_NODES + dst], 1);
  if (slot < CAP) pool[(et * N_NODES + dst) * CAP + slot] = src;
}

__global__ void sortrows_kernel(const int* __restrict__ cnt, const int* __restrict__ pool,
                                int* __restrict__ nbr) {
  __shared__ int buf[64][CAP + 1];
  int idx = blockIdx.x * 64 + threadIdx.x;
  if (idx >= 4 * N_NODES) return;
  int n = idx % N_NODES;
  int c = cnt[idx];
  if (c > CAP) c = CAP;
  int* a = buf[threadIdx.x];
  const int* row = pool + idx * CAP;
  for (int j = 0; j < c; ++j) a[j] = row[j] * 2;
  a[c] = n * 2 + 1;  // self loop sorts after equal-src originals (stable argsort semantics)
  ++c;
  for (int i2 = 1; i2 < c; ++i2) {
    int key = a[i2];
    int b = i2 - 1;
    while (b >= 0 && a[b] > key) { a[b + 1] = a[b]; --b; }
    a[b + 1] = key;
  }
  int* onbr = nbr + idx * MAXD;
  for (int t = 0; t < MAXD; ++t) onbr[t] = (t < c) ? (a[t] >> 1) : N_NODES;
}

__global__ void zero_dummy_kernel(float* __restrict__ ybase) {
  int tid = threadIdx.x;
#pragma unroll
  for (int et = 0; et < 4; ++et)
    ybase[(size_t)et * YROW + (size_t)N_NODES * 256 + tid] = 0.0f;
}

// ---------------- 256x64 weight -> fragment-ordered bf16 hi/lo ----------------
// combo = ((i*4 + w)*4 + g)*2 + kc ; per combo hi block then lo block, 64 lanes x short8.
// B-frag: lane n=l&15 -> row g*64+16w+n ; k = kc*32 + (l>>4)*8 + j.

__global__ __launch_bounds__(256) void prep_wfrag_kernel(const float* __restrict__ W,
                                                         short* __restrict__ w16) {
  int gid = blockIdx.x * 256 + threadIdx.x;
  if (gid >= 384 * 64) return;
  int lane = gid & 63;
  int combo = gid >> 6;
  int kc = combo & 1;
  int g = (combo >> 1) & 3;
  int w = (combo >> 3) & 3;
  int i = combo >> 5;
  int gate = g * 64 + w * 16 + (lane & 15);
  int k0 = kc * 32 + (lane >> 4) * 8;
  const float* src = W + ((size_t)i * 256 + gate) * 64 + k0;
  float4 a = ((const float4*)src)[0];
  float4 b = ((const float4*)src)[1];
  short8 hi, lo;
  split_frag(a, b, hi, lo);
  short8* dst = (short8*)w16;
  dst[(combo * 2 + 0) * 64 + lane] = hi;
  dst[(combo * 2 + 1) * 64 + lane] = lo;
}

// ---------------- combine weights -> fragments (per layer/side: WlA, WlB, WrA+WrB) ----------
// 6 pairs (L,side) x 3 mats x 8 combos (w'*2+kc) x 64 lanes; hi/lo blocks of 64 short8.

__global__ __launch_bounds__(256) void prep_cw_kernel(const float* __restrict__ Wl,
    const float* __restrict__ Wr, short* __restrict__ cw) {
  int gid = blockIdx.x * 256 + threadIdx.x;
  if (gid >= 144 * 64) return;
  int lane = gid & 63;
  int rest = gid >> 6;
  int combo = rest & 7;         // w'*2 + kc
  int mat = (rest >> 3) % 3;
  int pair = rest / 24;         // L*2 + side
  int L = pair >> 1, side = pair & 1;
  int iA = L * 4 + (side ? 1 : 0);
  int iB = L * 4 + (side ? 2 : 3);
  int wp = combo >> 1, kc = combo & 1;
  int row = wp * 16 + (lane & 15);
  int k0 = kc * 32 + (lane >> 4) * 8;
  float4 a, b;
  if (mat == 0) {
    const float* s = Wl + ((size_t)iA * 64 + row) * 64 + k0;
    a = ((const float4*)s)[0]; b = ((const float4*)s)[1];
  } else if (mat == 1) {
    const float* s = Wl + ((size_t)iB * 64 + row) * 64 + k0;
    a = ((const float4*)s)[0]; b = ((const float4*)s)[1];
  } else {
    const float* sA = Wr + ((size_t)iA * 64 + row) * 64 + k0;
    const float* sB = Wr + ((size_t)iB * 64 + row) * 64 + k0;
    float4 a1 = ((const float4*)sA)[0], b1 = ((const float4*)sA)[1];
    float4 a2 = ((const float4*)sB)[0], b2 = ((const float4*)sB)[1];
    a.x = a1.x + a2.x; a.y = a1.y + a2.y; a.z = a1.z + a2.z; a.w = a1.w + a2.w;
    b.x = b1.x + b2.x; b.y = b1.y + b2.y; b.z = b1.z + b2.z; b.w = b1.w + b2.w;
  }
  short8 hi, lo;
  split_frag(a, b, hi, lo);
  short8* dst = (short8*)cw;
  int base = ((pair * 3 + mat) * 8 + combo) * 2;
  dst[(base + 0) * 64 + lane] = hi;
  dst[(base + 1) * 64 + lane] = lo;
}

// ---------------- node encoders ----------------

template <int IN>
__global__ __launch_bounds__(256) void encode_kernel(const float* __restrict__ x,
    const float* __restrict__ W1, const float* __restrict__ b1,
    const float* __restrict__ W2, const float* __restrict__ b2, float* __restrict__ out) {
  __shared__ float xs[4][IN];
  __shared__ float h1[4][HD];
  int w = threadIdx.x >> 6, l = threadIdx.x & 63;
  int n = blockIdx.x * 4 + w;
  if (l < IN) xs[w][l] = x[n * IN + l];
  __syncthreads();
  float acc = b1[l];
#pragma unroll
  for (int k = 0; k < IN; ++k) acc = fmaf(xs[w][k], W1[l * IN + k], acc);
  h1[w][l] = fmaxf(acc, 0.0f);
  __syncthreads();
  float acc2 = b2[l];
#pragma unroll
  for (int k = 0; k < HD; ++k) acc2 = fmaf(h1[w][k], W2[l * HD + k], acc2);
  out[n * HD + l] = acc2;
}

// ---------------- y = x @ Wih.T via MFMA split-bf16; layout [node][u*4+g] ----------------
// grid (625, 4). Wave w = gate g=w; subtiles w'=0..3 cover its 64 units.

__global__ __launch_bounds__(256) void ygemm_mfma_kernel(const float* __restrict__ xs0,
    const float* __restrict__ xt0, const short* __restrict__ wih16L, float* __restrict__ ybase) {
  __shared__ __align__(16) float xS[16][68];
  __shared__ __align__(16) float pS[16][260];
  int et = blockIdx.y;
  const float* x = (et == 0 || et == 2) ? xs0 : xt0;
  const short8* wf = (const short8*)(wih16L + (size_t)et * 32768);
  float* y = ybase + (size_t)et * YROW;
  int tid = threadIdx.x, w = tid >> 6, l = tid & 63;
  int quad = l >> 4, n = l & 15;
  int n0 = blockIdx.x * 16;
  {
    int node = tid >> 4, f4 = tid & 15;
    float4 v = *(const float4*)(x + (size_t)(n0 + node) * 64 + f4 * 4);
    *(float4*)&xS[node][f4 * 4] = v;
  }
  short8 Bh[4][2], Bl[4][2];
#pragma unroll
  for (int wp = 0; wp < 4; ++wp)
#pragma unroll
    for (int kc = 0; kc < 2; ++kc) {
      int combo = (wp * 4 + w) * 2 + kc;
      Bh[wp][kc] = wf[(combo * 2 + 0) * 64 + l];
      Bl[wp][kc] = wf[(combo * 2 + 1) * 64 + l];
    }
  __syncthreads();
  short8 Ah[2], Al[2];
  {
    const float* hp = &xS[n][quad * 8];
    float4 q0 = *(const float4*)hp, q1 = *(const float4*)(hp + 4);
    float4 q2 = *(const float4*)(hp + 32), q3 = *(const float4*)(hp + 36);
    split_frag(q0, q1, Ah[0], Al[0]);
    split_frag(q2, q3, Ah[1], Al[1]);
  }
  floatx4 acc[4];
#pragma unroll
  for (int wp = 0; wp < 4; ++wp) {
    floatx4 a = {0.f, 0.f, 0.f, 0.f};
    a = MFMA16(Ah[0], Bh[wp][0], a);
    a = MFMA16(Ah[1], Bh[wp][1], a);
    a = MFMA16(Al[0], Bh[wp][0], a);
    a = MFMA16(Al[1], Bh[wp][1], a);
    a = MFMA16(Ah[0], Bl[wp][0], a);
    a = MFMA16(Ah[1], Bl[wp][1], a);
    acc[wp] = a;
  }
#pragma unroll
  for (int wp = 0; wp < 4; ++wp)
#pragma unroll
    for (int r = 0; r < 4; ++r)
      pS[quad * 4 + r][(wp * 16 + n) * 4 + w] = acc[wp][r];
  __syncthreads();
#pragma unroll
  for (int cc = 0; cc < 4; ++cc) {
    int g4 = cc * 256 + tid;
    int node = g4 >> 6, col = g4 & 63;
    float4 v = *(const float4*)&pS[node][col * 4];
    ((float4*)(y + (size_t)(n0 + node) * 256))[col] = v;
  }
}

// ---------------- SAGE-LSTM aggregation, MFMA split-bf16, 4 edge types ----------------

__global__ __launch_bounds__(256) void lstm_mfma_kernel(const int* __restrict__ nbrAll,
    const float* __restrict__ ybase, const short* __restrict__ whh16L,
    const float* __restrict__ bihL, const float* __restrict__ bhhL, float* __restrict__ aggBase) {
  __shared__ __align__(16) unsigned pkS[2][16 * 68];
  __shared__ int nbS[16][MAXD];
  int et = blockIdx.y;
  const int* nbr = nbrAll + (size_t)et * N_NODES * MAXD;
  const float4* y4 = (const float4*)(ybase + (size_t)et * YROW);
  const short* whh16 = whh16L + (size_t)et * 32768;
  const float* bih = bihL + et * 256;
  const float* bhh = bhhL + et * 256;
  float* agg = aggBase + (size_t)et * N_NODES * HD;
  int tid = threadIdx.x, w = tid >> 6, l = tid & 63;
  int quad = l >> 4, n = l & 15, u = w * 16 + n;
  int n0 = blockIdx.x * 16;
  if (tid < 16 * MAXD) ((int*)nbS)[tid] = nbr[n0 * MAXD + tid];
  short8 Bh[4][2], Bl[4][2];
  {
    const short8* wf = (const short8*)whh16;
#pragma unroll
    for (int g = 0; g < 4; ++g)
#pragma unroll
      for (int kc = 0; kc < 2; ++kc) {
        int combo = (w * 4 + g) * 2 + kc;
        Bh[g][kc] = wf[(combo * 2 + 0) * 64 + l];
        Bl[g][kc] = wf[(combo * 2 + 1) * 64 + l];
      }
  }
  float bs[4];
#pragma unroll
  for (int g = 0; g < 4; ++g) bs[g] = bih[g * 64 + u] + bhh[g * 64 + u];
  float c[4] = {0.f, 0.f, 0.f, 0.f}, h[4];
  short8 Ah[2], Al[2];
#pragma unroll
  for (int kc = 0; kc < 2; ++kc) { Ah[kc] = (short8)0; Al[kc] = (short8)0; }
  __syncthreads();
  float4 Y[4];
#pragma unroll
  for (int r = 0; r < 4; ++r) Y[r] = y4[(size_t)nbS[quad * 4 + r][0] * 64 + u];
  for (int t = 0; t < MAXD; ++t) {
    float yg[4][4];
#pragma unroll
    for (int r = 0; r < 4; ++r) {
      yg[0][r] = Y[r].x; yg[1][r] = Y[r].y; yg[2][r] = Y[r].z; yg[3][r] = Y[r].w;
    }
    floatx4 acc[4];
#pragma unroll
    for (int g = 0; g < 4; ++g) {
      floatx4 a = {yg[g][0], yg[g][1], yg[g][2], yg[g][3]};
      a = MFMA16(Ah[0], Bh[g][0], a);
      a = MFMA16(Ah[1], Bh[g][1], a);
      a = MFMA16(Al[0], Bh[g][0], a);
      a = MFMA16(Al[1], Bh[g][1], a);
      a = MFMA16(Ah[0], Bl[g][0], a);
      a = MFMA16(Ah[1], Bl[g][1], a);
      acc[g] = a;
    }
    if (t + 1 < MAXD) {
#pragma unroll
      for (int r = 0; r < 4; ++r) Y[r] = y4[(size_t)nbS[quad * 4 + r][t + 1] * 64 + u];
    }
    int buf = (t + 1) & 1;
    // gate math, shared-rcp: sigma(f)c + sigma(i)tanh(g) over one denominator,
    // sigma(o)tanh(c) over another. 5 exp + 2 rcp per (node,unit).
#pragma unroll
    for (int r = 0; r < 4; ++r) {
      float gi = acc[0][r] + bs[0];
      float gf = acc[1][r] + bs[1];
      float gg = acc[2][r] + bs[2];
      float go = acc[3][r] + bs[3];
      float a_ = __expf(-gi);
      float b_ = __expf(fminf(-(gg + gg), 60.f));
      float f_ = __expf(-gf);
      float o_ = __expf(-go);
      float p1 = 1.f + a_, p2 = 1.f + b_, p3 = 1.f + f_;
      float d1 = p1 * p2;
      float num = fmaf(c[r], d1, (1.f - b_) * p3);
      c[r] = num * __builtin_amdgcn_rcpf(p3 * d1);
      float e_ = __expf(-(c[r] + c[r]));
      h[r] = (1.f - e_) * __builtin_amdgcn_rcpf((1.f + e_) * (1.f + o_));
      unsigned ub = __float_as_uint(h[r]);
      float lo = h[r] - __uint_as_float(ub & 0xFFFF0000u);
      pkS[buf][(quad * 4 + r) * 68 + u] =
          __builtin_amdgcn_perm(ub, __float_as_uint(lo), 0x07060302u);
    }
    __syncthreads();
    if (t + 1 < MAXD) {
#pragma unroll
      for (int kc = 0; kc < 2; ++kc) {
        const unsigned* pb = &pkS[buf][n * 68 + kc * 32 + quad * 8];
        uint4 qa = *(const uint4*)pb;
        uint4 qb = *(const uint4*)(pb + 4);
        union { short8 s; unsigned d[4]; } H, L;
        H.d[0] = __builtin_amdgcn_perm(qa.y, qa.x, 0x07060302u);
        H.d[1] = __builtin_amdgcn_perm(qa.w, qa.z, 0x07060302u);
        H.d[2] = __builtin_amdgcn_perm(qb.y, qb.x, 0x07060302u);
        H.d[3] = __builtin_amdgcn_perm(qb.w, qb.z, 0x07060302u);
        L.d[0] = __builtin_amdgcn_perm(qa.y, qa.x, 0x05040100u);
        L.d[1] = __builtin_amdgcn_perm(qa.w, qa.z, 0x05040100u);
        L.d[2] = __builtin_amdgcn_perm(qb.y, qb.x, 0x05040100u);
        L.d[3] = __builtin_amdgcn_perm(qb.w, qb.z, 0x05040100u);
        Ah[kc] = H.s;
        Al[kc] = L.s;
      }
    }
  }
#pragma unroll
  for (int r = 0; r < 4; ++r)
    agg[(size_t)(n0 + quad * 4 + r) * HD + u] = h[r];
}

// ---------------- combine via MFMA: 0.5*(WlA.aA + WlB.aB + (WrA+WrB).x + blA+blB) + res ----
// grid (625, 2). Wave w = N-subtile w (16 units); 3 mats x 6 MFMA.

__global__ __launch_bounds__(256) void combine_mfma_kernel(const float* __restrict__ aggBase,
    const short* __restrict__ cwL, const float* __restrict__ blL,
    const float* __restrict__ xS0, const float* __restrict__ xT0, int has_res,
    float* __restrict__ outS, float* __restrict__ outT) {
  __shared__ __align__(16) float tS[3][16][68];
  int side = blockIdx.y;
  int etA = side ? 1 : 0, etB = side ? 2 : 3;
  const float* srcs[3];
  srcs[0] = aggBase + (size_t)etA * N_NODES * HD;
  srcs[1] = aggBase + (size_t)etB * N_NODES * HD;
  srcs[2] = side ? xT0 : xS0;
  float* out = side ? outT : outS;
  const short8* wf = (const short8*)cwL + (size_t)side * 3072;
  const float* blA = blL + etA * 64;
  const float* blB = blL + etB * 64;
  int tid = threadIdx.x, w = tid >> 6, l = tid & 63;
  int quad = l >> 4, n = l & 15;
  int n0 = blockIdx.x * 16;
  {
    int node = tid >> 4, f4 = tid & 15;
#pragma unroll
    for (int m = 0; m < 3; ++m) {
      float4 v = *(const float4*)(srcs[m] + (size_t)(n0 + node) * 64 + f4 * 4);
      *(float4*)&tS[m][node][f4 * 4] = v;
    }
  }
  short8 Bh[3][2], Bl[3][2];
#pragma unroll
  for (int m = 0; m < 3; ++m)
#pragma unroll
    for (int kc = 0; kc < 2; ++kc) {
      int base = (m * 8 + w * 2 + kc) * 2;
      Bh[m][kc] = wf[(base + 0) * 64 + l];
      Bl[m][kc] = wf[(base + 1) * 64 + l];
    }
  float bsum = blA[w * 16 + n] + blB[w * 16 + n];
  __syncthreads();
  floatx4 a = {0.f, 0.f, 0.f, 0.f};
#pragma unroll
  for (int m = 0; m < 3; ++m) {
    short8 Ah[2], Al[2];
    const float* hp = &tS[m][n][quad * 8];
    float4 q0 = *(const float4*)hp, q1 = *(const float4*)(hp + 4);
    float4 q2 = *(const float4*)(hp + 32), q3 = *(const float4*)(hp + 36);
    split_frag(q0, q1, Ah[0], Al[0]);
    split_frag(q2, q3, Ah[1], Al[1]);
    a = MFMA16(Ah[0], Bh[m][0], a);
    a = MFMA16(Ah[1], Bh[m][1], a);
    a = MFMA16(Al[0], Bh[m][0], a);
    a = MFMA16(Al[1], Bh[m][1], a);
    a = MFMA16(Ah[0], Bl[m][0], a);
    a = MFMA16(Ah[1], Bl[m][1], a);
  }
#pragma unroll
  for (int r = 0; r < 4; ++r) {
    int node = quad * 4 + r;
    float v = 0.5f * (a[r] + bsum);
    if (has_res) v += tS[2][node][w * 16 + n];
    out[(size_t)(n0 + node) * 64 + w * 16 + n] = fmaxf(v, 0.f);
  }
}

// ---------------- edge head ----------------

__global__ __launch_bounds__(256) void edge_head_kernel(
    const int* __restrict__ esrc, const int* __restrict__ edst, const float* __restrict__ ea,
    const float* __restrict__ s3, const float* __restrict__ t3,
    const float* __restrict__ Wg1, const float* __restrict__ bg1,
    const float* __restrict__ Wg2, const float* __restrict__ bg2,
    const float* __restrict__ Wm1, const float* __restrict__ bm1,
    const float* __restrict__ Wm2, const float* __restrict__ bm2,
    const float* __restrict__ Wm3, const float* __restrict__ bm3,
    float* __restrict__ out) {
  __shared__ __align__(16) float4 xS[64][32];
  __shared__ __align__(16) float4 eaS[64][4];
  int tid = threadIdx.x, w = tid >> 6, l = tid & 63;
  int e0 = blockIdx.x * 64;
  for (int idx = tid; idx < 2048; idx += 256) {
    int e = idx >> 5, kk = idx & 31;
    float4 v;
    if (kk < 16) v = ((const float4*)(s3 + (size_t)esrc[e0 + e] * 64))[kk];
    else         v = ((const float4*)(t3 + (size_t)edst[e0 + e] * 64))[kk - 16];
    xS[e][kk] = v;
  }
  {
    int e = tid >> 2, kk = tid & 3;
    eaS[e][kk] = ((const float4*)(ea + (size_t)(e0 + e) * 16))[kk];
  }
  __syncthreads();
  {
    float4 wr[32];
    const float4* W4 = (const float4*)(Wg1 + l * 128);
#pragma unroll
    for (int kk = 0; kk < 32; ++kk) wr[kk] = W4[kk];
    float bg = bg1[l], w2 = Wg2[l], b2 = bg2[0];
    for (int m0 = 0; m0 < 16; m0 += 4) {
      int e = w * 16 + m0;
      float a0 = bg, a1 = bg, a2 = bg, a3 = bg;
#pragma unroll
      for (int kk = 0; kk < 32; ++kk) {
        float4 wv = wr[kk];
        a0 = fma4(wv, xS[e + 0][kk], a0);
        a1 = fma4(wv, xS[e + 1][kk], a1);
        a2 = fma4(wv, xS[e + 2][kk], a2);
        a3 = fma4(wv, xS[e + 3][kk], a3);
      }
      a0 = fmaxf(a0, 0.f) * w2; a1 = fmaxf(a1, 0.f) * w2;
      a2 = fmaxf(a2, 0.f) * w2; a3 = fmaxf(a3, 0.f) * w2;
#pragma unroll
      for (int off = 32; off; off >>= 1) {
        a0 += __shfl_xor(a0, off); a1 += __shfl_xor(a1, off);
        a2 += __shfl_xor(a2, off); a3 += __shfl_xor(a3, off);
      }
      float g0 = sigmoidf_(a0 + b2), g1 = sigmoidf_(a1 + b2);
      float g2 = sigmoidf_(a2 + b2), g3 = sigmoidf_(a3 + b2);
      float* r0 = (float*)xS[e + 0]; float* r1 = (float*)xS[e + 1];
      float* r2 = (float*)xS[e + 2]; float* r3 = (float*)xS[e + 3];
      r0[l] = fmaf(g0, r0[l] - r0[64 + l], r0[64 + l]);
      r1[l] = fmaf(g1, r1[l] - r1[64 + l], r1[64 + l]);
      r2[l] = fmaf(g2, r2[l] - r2[64 + l], r2[64 + l]);
      r3[l] = fmaf(g3, r3[l] - r3[64 + l], r3[64 + l]);
    }
  }
  __syncthreads();
  {
    float4 wr[20];
    const float4* W4 = (const float4*)(Wm1 + l * 80);
#pragma unroll
    for (int kk = 0; kk < 20; ++kk) wr[kk] = W4[kk];
    float bm = bm1[l];
    float h2v[16];
    for (int m0 = 0; m0 < 16; m0 += 4) {
      int e = w * 16 + m0;
      float a0 = bm, a1 = bm, a2 = bm, a3 = bm;
#pragma unroll
      for (int kk = 0; kk < 16; ++kk) {
        float4 wv = wr[kk];
        a0 = fma4(wv, xS[e + 0][kk], a0);
        a1 = fma4(wv, xS[e + 1][kk], a1);
        a2 = fma4(wv, xS[e + 2][kk], a2);
        a3 = fma4(wv, xS[e + 3][kk], a3);
      }
#pragma unroll
      for (int kk = 0; kk < 4; ++kk) {
        float4 wv = wr[16 + kk];
        a0 = fma4(wv, eaS[e + 0][kk], a0);
        a1 = fma4(wv, eaS[e + 1][kk], a1);
        a2 = fma4(wv, eaS[e + 2][kk], a2);
        a3 = fma4(wv, eaS[e + 3][kk], a3);
      }
      h2v[m0 + 0] = fmaxf(a0, 0.f); h2v[m0 + 1] = fmaxf(a1, 0.f);
      h2v[m0 + 2] = fmaxf(a2, 0.f); h2v[m0 + 3] = fmaxf(a3, 0.f);
    }
#pragma unroll
    for (int m = 0; m < 16; ++m) ((float*)xS[w * 16 + m])[64 + l] = h2v[m];
  }
  __syncthreads();
  {
    int half = l >> 5, j = l & 31;
    float4 wr[16];
    const float4* W4 = (const float4*)(Wm2 + j * 64);
#pragma unroll
    for (int kk = 0; kk < 16; ++kk) wr[kk] = W4[kk];
    float bm = bm2[j], w3a = Wm3[j], w3b = Wm3[32 + j];
    float b3a = bm3[0], b3b = bm3[1];
    for (int mg = 0; mg < 16; mg += 2) {
      int m = mg + half, e = w * 16 + m;
      float acc = bm;
#pragma unroll
      for (int kk = 0; kk < 16; ++kk) acc = fma4(wr[kk], xS[e][16 + kk], acc);
      float h3 = fmaxf(acc, 0.f);
      float p0 = h3 * w3a, p1 = h3 * w3b;
#pragma unroll
      for (int off = 16; off; off >>= 1) {
        p0 += __shfl_xor(p0, off);
        p1 += __shfl_xor(p1, off);
      }
      if (j == 0) {
        int ge = e0 + e;
        out[ge * 2 + 0] = p0 + b3a;
        out[ge * 2 + 1] = p1 + b3b;
      }
    }
  }
}

// ---------------- host orchestration ----------------

extern "C" void kernel_launch(void* const* d_in, const int* in_sizes, int n_in, void* d_out,
                              int out_size, void* d_ws, size_t ws_size, hipStream_t stream) {
  const float* x_source = (const float*)d_in[0];
  const float* x_target = (const float*)d_in[1];
  const int* edges = (const int*)d_in[2];
  const float* edge_attr = (const float*)d_in[3];
  const float* We_s1 = (const float*)d_in[4];
  const float* be_s1 = (const float*)d_in[5];
  const float* We_s2 = (const float*)d_in[6];
  const float* be_s2 = (const float*)d_in[7];
  const float* We_t1 = (const float*)d_in[8];
  const float* be_t1 = (const float*)d_in[9];
  const float* We_t2 = (const float*)d_in[10];
  const float* be_t2 = (const float*)d_in[11];
  const float* Wih = (const float*)d_in[12];
  const float* Whh = (const float*)d_in[13];
  const float* bih = (const float*)d_in[14];
  const float* bhh = (const float*)d_in[15];
  const float* Wl = (const float*)d_in[16];
  const float* bl = (const float*)d_in[17];
  const float* Wr = (const float*)d_in[18];
  const float* Wg1 = (const float*)d_in[19];
  const float* bg1 = (const float*)d_in[20];
  const float* Wg2 = (const float*)d_in[21];
  const float* bg2 = (const float*)d_in[22];
  const float* Wm1 = (const float*)d_in[23];
  const float* bm1 = (const float*)d_in[24];
  const float* Wm2 = (const float*)d_in[25];
  const float* bm2 = (const float*)d_in[26];
  const float* Wm3 = (const float*)d_in[27];
  const float* bm3 = (const float*)d_in[28];
  float* out = (float*)d_out;

  int* nbr = (int*)d_ws;                       // 4*N*12
  int* cnt = nbr + 4 * N_NODES * MAXD;         // 4*N
  int* pool = cnt + 4 * N_NODES;               // 4*N*CAP
  float* fb = (float*)(pool + 4 * N_NODES * CAP);
  float* bufS[2] = {fb, fb + N_NODES * HD};
  float* bufT[2] = {fb + 2 * N_NODES * HD, fb + 3 * N_NODES * HD};
  float* aggBase = fb + (size_t)4 * N_NODES * HD;        // 4 * N*64
  float* y4 = fb + (size_t)8 * N_NODES * HD;             // 4 * (N+1)*256
  short* whh16 = (short*)(y4 + 4 * YROW);                // 12 * 32768
  short* wih16 = whh16 + 12 * 32768;                     // 12 * 32768
  short* cw16 = wih16 + 12 * 32768;                      // 6 * 24576

  hipMemsetAsync(cnt, 0, 4 * N_NODES * sizeof(int), stream);
  prep_wfrag_kernel<<<96, 256, 0, stream>>>(Whh, whh16);
  prep_wfrag_kernel<<<96, 256, 0, stream>>>(Wih, wih16);
  prep_cw_kernel<<<36, 256, 0, stream>>>(Wl, Wr, cw16);
  zero_dummy_kernel<<<1, 256, 0, stream>>>(y4);
  scatter_kernel<<<(4 * N_EDGES + 255) / 256, 256, 0, stream>>>(edges, cnt, pool);
  sortrows_kernel<<<(4 * N_NODES + 63) / 64, 64, 0, stream>>>(cnt, pool, nbr);
  encode_kernel<32><<<N_NODES / 4, 256, 0, stream>>>(x_source, We_s1, be_s1, We_s2, be_s2, bufS[0]);
  encode_kernel<24><<<N_NODES / 4, 256, 0, stream>>>(x_target, We_t1, be_t1, We_t2, be_t2, bufT[0]);

  int cur = 0;
  for (int L = 0; L < 3; ++L) {
    ygemm_mfma_kernel<<<dim3(N_NODES / 16, 4), 256, 0, stream>>>(bufS[cur], bufT[cur],
        wih16 + (size_t)L * 4 * 32768, y4);
    lstm_mfma_kernel<<<dim3(N_NODES / 16, 4), 256, 0, stream>>>(nbr, y4,
        whh16 + (size_t)L * 4 * 32768, bih + L * 1024, bhh + L * 1024, aggBase);
    combine_mfma_kernel<<<dim3(N_NODES / 16, 2), 256, 0, stream>>>(aggBase,
        cw16 + (size_t)L * 2 * 24576, bl + L * 256,
        bufS[cur], bufT[cur], L > 0 ? 1 : 0, bufS[1 - cur], bufT[1 - cur]);
    cur = 1 - cur;
  }

  edge_head_kernel<<<N_EDGES / 64, 256, 0, stream>>>(edges + 4 * N_EDGES, edges + 5 * N_EDGES,
      edge_attr, bufS[cur], bufT[cur], Wg1, bg1, Wg2, bg2, Wm1, bm1, Wm2, bm2, Wm3, bm3, out);
}

// Round 7
// 444.353 us; speedup vs baseline: 5.7921x; 1.1013x over previous
//
#include <hip/hip_runtime.h>

#define N_NODES 10000
#define N_EDGES 40000
#define HD 64
#define MAXD 12
#define CAP 32
#define YROW ((size_t)(N_NODES + 1) * 256)  // per-edge-type y stride, +1 dummy zero row
#define LOG2E 1.44269504f
#define XST 148  // edge-head LDS row stride (floats): [se|te]=128, ea=16, pad 4

typedef __attribute__((ext_vector_type(8))) short short8;
typedef __attribute__((ext_vector_type(4))) float floatx4;

#define MFMA16(A, B, C) __builtin_amdgcn_mfma_f32_16x16x32_bf16(A, B, C, 0, 0, 0)

#if __has_builtin(__builtin_amdgcn_exp2f)
#define EXP2(x) __builtin_amdgcn_exp2f(x)
#else
#define EXP2(x) __expf((x) * 0.6931471806f)
#endif

__device__ __forceinline__ float sigmoidf_(float x) {
  return 1.0f / (1.0f + __expf(-x));
}
__device__ __forceinline__ float fma4(float4 w, float4 x, float a) {
  a = fmaf(w.x, x.x, a);
  a = fmaf(w.y, x.y, a);
  a = fmaf(w.z, x.z, a);
  return fmaf(w.w, x.w, a);
}

// split 8 consecutive fp32 into bf16 hi/lo fragments
__device__ __forceinline__ void split_frag(float4 a, float4 b, short8& hi, short8& lo) {
  float f[8] = {a.x, a.y, a.z, a.w, b.x, b.y, b.z, b.w};
  union { short8 v; unsigned d[4]; } H, L;
#pragma unroll
  for (int p = 0; p < 4; ++p) {
    unsigned u0 = __float_as_uint(f[2 * p]);
    unsigned u1 = __float_as_uint(f[2 * p + 1]);
    H.d[p] = (u0 >> 16) | (u1 & 0xFFFF0000u);
    float l0 = f[2 * p] - __uint_as_float(u0 & 0xFFFF0000u);
    float l1 = f[2 * p + 1] - __uint_as_float(u1 & 0xFFFF0000u);
    L.d[p] = (__float_as_uint(l0) >> 16) | (__float_as_uint(l1) & 0xFFFF0000u);
  }
  hi = H.v;
  lo = L.v;
}

// ---------------- adjacency build ----------------

__global__ void scatter_kernel(const int* __restrict__ edges, int* __restrict__ cnt,
                               int* __restrict__ pool) {
  int idx = blockIdx.x * 256 + threadIdx.x;
  if (idx >= 4 * N_EDGES) return;
  int et = idx / N_EDGES, e = idx - et * N_EDGES;
  int src = edges[(et * 2) * N_EDGES + e];
  int dst = edges[(et * 2 + 1) * N_EDGES + e];
  int slot = atomicAdd(&cnt[et * N_NODES + dst], 1);
  if (slot < CAP) pool[(et * N_NODES + dst) * CAP + slot] = src;
}

__global__ void sortrows_kernel(const int* __restrict__ cnt, const int* __restrict__ pool,
                                int* __restrict__ nbr) {
  __shared__ int buf[64][CAP + 1];
  int idx = blockIdx.x * 64 + threadIdx.x;
  if (idx >= 4 * N_NODES) return;
  int n = idx % N_NODES;
  int c = cnt[idx];
  if (c > CAP) c = CAP;
  int* a = buf[threadIdx.x];
  const int* row = pool + idx * CAP;
  for (int j = 0; j < c; ++j) a[j] = row[j] * 2;
  a[c] = n * 2 + 1;  // self loop sorts after equal-src originals (stable argsort semantics)
  ++c;
  for (int i2 = 1; i2 < c; ++i2) {
    int key = a[i2];
    int b = i2 - 1;
    while (b >= 0 && a[b] > key) { a[b + 1] = a[b]; --b; }
    a[b + 1] = key;
  }
  int* onbr = nbr + idx * MAXD;
  for (int t = 0; t < MAXD; ++t) onbr[t] = (t < c) ? (a[t] >> 1) : N_NODES;
}

// ---------------- fused weight prep ----------------
// Whh/Wih frags scaled by log2e (cell gate by 2*log2e) so lstm uses raw exp2.

__device__ __forceinline__ void wfrag_body(const float* __restrict__ W,
                                           short* __restrict__ w16, int gid) {
  int lane = gid & 63;
  int combo = gid >> 6;
  int kc = combo & 1;
  int g = (combo >> 1) & 3;
  int w = (combo >> 3) & 3;
  int i = combo >> 5;
  float sc = (g == 2) ? (2.0f * LOG2E) : LOG2E;
  int gate = g * 64 + w * 16 + (lane & 15);
  int k0 = kc * 32 + (lane >> 4) * 8;
  const float* src = W + ((size_t)i * 256 + gate) * 64 + k0;
  float4 a = ((const float4*)src)[0];
  float4 b = ((const float4*)src)[1];
  a.x *= sc; a.y *= sc; a.z *= sc; a.w *= sc;
  b.x *= sc; b.y *= sc; b.z *= sc; b.w *= sc;
  short8 hi, lo;
  split_frag(a, b, hi, lo);
  short8* dst = (short8*)w16;
  dst[(combo * 2 + 0) * 64 + lane] = hi;
  dst[(combo * 2 + 1) * 64 + lane] = lo;
}

__device__ __forceinline__ void cw_body(const float* __restrict__ Wl,
    const float* __restrict__ Wr, short* __restrict__ cw, int gid) {
  int lane = gid & 63;
  int rest = gid >> 6;
  int combo = rest & 7;
  int mat = (rest >> 3) % 3;
  int pair = rest / 24;
  int L = pair >> 1, side = pair & 1;
  int iA = L * 4 + (side ? 1 : 0);
  int iB = L * 4 + (side ? 2 : 3);
  int wp = combo >> 1, kc = combo & 1;
  int row = wp * 16 + (lane & 15);
  int k0 = kc * 32 + (lane >> 4) * 8;
  float4 a, b;
  if (mat == 0) {
    const float* s = Wl + ((size_t)iA * 64 + row) * 64 + k0;
    a = ((const float4*)s)[0]; b = ((const float4*)s)[1];
  } else if (mat == 1) {
    const float* s = Wl + ((size_t)iB * 64 + row) * 64 + k0;
    a = ((const float4*)s)[0]; b = ((const float4*)s)[1];
  } else {
    const float* sA = Wr + ((size_t)iA * 64 + row) * 64 + k0;
    const float* sB = Wr + ((size_t)iB * 64 + row) * 64 + k0;
    float4 a1 = ((const float4*)sA)[0], b1 = ((const float4*)sA)[1];
    float4 a2 = ((const float4*)sB)[0], b2 = ((const float4*)sB)[1];
    a.x = a1.x + a2.x; a.y = a1.y + a2.y; a.z = a1.z + a2.z; a.w = a1.w + a2.w;
    b.x = b1.x + b2.x; b.y = b1.y + b2.y; b.z = b1.z + b2.z; b.w = b1.w + b2.w;
  }
  short8 hi, lo;
  split_frag(a, b, hi, lo);
  short8* dst = (short8*)cw;
  int base = ((pair * 3 + mat) * 8 + combo) * 2;
  dst[(base + 0) * 64 + lane] = hi;
  dst[(base + 1) * 64 + lane] = lo;
}

// edge-head weights: Wg1[64x128] combos 0..15 (wp*4+kc), Wm1[64x80] 16..27
// (16+wp*3+kc, kc=2 zero-padded past K=80), Wm2[32x64] 28..31 (28+wp*2+kc).
__device__ __forceinline__ void eh_body(const float* __restrict__ Wg1,
    const float* __restrict__ Wm1, const float* __restrict__ Wm2,
    short* __restrict__ ehw16, int gid) {
  int lane = gid & 63;
  int combo = gid >> 6;
  int n = lane & 15, quad = lane >> 4;
  int mat, wp, kc;
  if (combo < 16) { mat = 0; wp = combo >> 2; kc = combo & 3; }
  else if (combo < 28) { int c2 = combo - 16; mat = 1; wp = c2 / 3; kc = c2 % 3; }
  else { int c2 = combo - 28; mat = 2; wp = c2 >> 1; kc = c2 & 1; }
  int row = wp * 16 + n;
  int k0 = kc * 32 + quad * 8;
  float4 a = {0.f, 0.f, 0.f, 0.f}, b = {0.f, 0.f, 0.f, 0.f};
  if (mat == 0) {
    const float* s = Wg1 + (size_t)row * 128 + k0;
    a = ((const float4*)s)[0]; b = ((const float4*)s)[1];
  } else if (mat == 1) {
    if (k0 + 8 <= 80) {
      const float* s = Wm1 + (size_t)row * 80 + k0;
      a = ((const float4*)s)[0]; b = ((const float4*)s)[1];
    }
  } else {
    const float* s = Wm2 + (size_t)row * 64 + k0;
    a = ((const float4*)s)[0]; b = ((const float4*)s)[1];
  }
  short8 hi, lo;
  split_frag(a, b, hi, lo);
  short8* dst = (short8*)ehw16;
  dst[(combo * 2 + 0) * 64 + lane] = hi;
  dst[(combo * 2 + 1) * 64 + lane] = lo;
}

__global__ __launch_bounds__(256) void prep_all_kernel(
    const float* __restrict__ Whh, const float* __restrict__ Wih,
    const float* __restrict__ Wl, const float* __restrict__ Wr,
    const float* __restrict__ Wg1, const float* __restrict__ Wm1,
    const float* __restrict__ Wm2,
    short* __restrict__ whh16, short* __restrict__ wih16, short* __restrict__ cw16,
    short* __restrict__ ehw16, float* __restrict__ ybase) {
  int gid = blockIdx.x * 256 + threadIdx.x;
  if (gid < 24576) {
    wfrag_body(Whh, whh16, gid);
  } else if (gid < 49152) {
    wfrag_body(Wih, wih16, gid - 24576);
  } else if (gid < 58368) {
    cw_body(Wl, Wr, cw16, gid - 49152);
  } else if (gid < 60416) {
    eh_body(Wg1, Wm1, Wm2, ehw16, gid - 58368);
  } else if (gid < 61440) {
    int t = gid - 60416;
    int et = t >> 8, col = t & 255;
    ybase[(size_t)et * YROW + (size_t)N_NODES * 256 + col] = 0.0f;
  }
}

// ---------------- node encoders (both types, one dispatch) ----------------

template <int IN>
__device__ __forceinline__ void encode_body(const float* __restrict__ x,
    const float* __restrict__ W1, const float* __restrict__ b1,
    const float* __restrict__ W2, const float* __restrict__ b2, float* __restrict__ out) {
  __shared__ float xs[4][IN];
  __shared__ float h1[4][HD];
  int w = threadIdx.x >> 6, l = threadIdx.x & 63;
  int n = blockIdx.x * 4 + w;
  if (l < IN) xs[w][l] = x[n * IN + l];
  __syncthreads();
  float acc = b1[l];
#pragma unroll
  for (int k = 0; k < IN; ++k) acc = fmaf(xs[w][k], W1[l * IN + k], acc);
  h1[w][l] = fmaxf(acc, 0.0f);
  __syncthreads();
  float acc2 = b2[l];
#pragma unroll
  for (int k = 0; k < HD; ++k) acc2 = fmaf(h1[w][k], W2[l * HD + k], acc2);
  out[n * HD + l] = acc2;
}

__global__ __launch_bounds__(256) void encode_both_kernel(
    const float* __restrict__ xs0, const float* __restrict__ xt0,
    const float* __restrict__ Ws1, const float* __restrict__ bs1,
    const float* __restrict__ Ws2, const float* __restrict__ bs2,
    const float* __restrict__ Wt1, const float* __restrict__ bt1,
    const float* __restrict__ Wt2, const float* __restrict__ bt2,
    float* __restrict__ outS, float* __restrict__ outT) {
  if (blockIdx.y == 0) encode_body<32>(xs0, Ws1, bs1, Ws2, bs2, outS);
  else encode_body<24>(xt0, Wt1, bt1, Wt2, bt2, outT);
}

// ---------------- y = x @ Wih.T via MFMA split-bf16; layout [node][u*4+g] ----------------

__global__ __launch_bounds__(256) void ygemm_mfma_kernel(const float* __restrict__ xs0,
    const float* __restrict__ xt0, const short* __restrict__ wih16L, float* __restrict__ ybase) {
  __shared__ __align__(16) float xS[16][68];
  __shared__ __align__(16) float pS[16][260];
  int et = blockIdx.y;
  const float* x = (et == 0 || et == 2) ? xs0 : xt0;
  const short8* wf = (const short8*)(wih16L + (size_t)et * 32768);
  float* y = ybase + (size_t)et * YROW;
  int tid = threadIdx.x, w = tid >> 6, l = tid & 63;
  int quad = l >> 4, n = l & 15;
  int n0 = blockIdx.x * 16;
  {
    int node = tid >> 4, f4 = tid & 15;
    float4 v = *(const float4*)(x + (size_t)(n0 + node) * 64 + f4 * 4);
    *(float4*)&xS[node][f4 * 4] = v;
  }
  short8 Bh[4][2], Bl[4][2];
#pragma unroll
  for (int wp = 0; wp < 4; ++wp)
#pragma unroll
    for (int kc = 0; kc < 2; ++kc) {
      int combo = (wp * 4 + w) * 2 + kc;
      Bh[wp][kc] = wf[(combo * 2 + 0) * 64 + l];
      Bl[wp][kc] = wf[(combo * 2 + 1) * 64 + l];
    }
  __syncthreads();
  short8 Ah[2], Al[2];
  {
    const float* hp = &xS[n][quad * 8];
    float4 q0 = *(const float4*)hp, q1 = *(const float4*)(hp + 4);
    float4 q2 = *(const float4*)(hp + 32), q3 = *(const float4*)(hp + 36);
    split_frag(q0, q1, Ah[0], Al[0]);
    split_frag(q2, q3, Ah[1], Al[1]);
  }
  floatx4 acc[4];
#pragma unroll
  for (int wp = 0; wp < 4; ++wp) {
    floatx4 a = {0.f, 0.f, 0.f, 0.f};
    a = MFMA16(Ah[0], Bh[wp][0], a);
    a = MFMA16(Ah[1], Bh[wp][1], a);
    a = MFMA16(Al[0], Bh[wp][0], a);
    a = MFMA16(Al[1], Bh[wp][1], a);
    a = MFMA16(Ah[0], Bl[wp][0], a);
    a = MFMA16(Ah[1], Bl[wp][1], a);
    acc[wp] = a;
  }
#pragma unroll
  for (int wp = 0; wp < 4; ++wp)
#pragma unroll
    for (int r = 0; r < 4; ++r)
      pS[quad * 4 + r][(wp * 16 + n) * 4 + w] = acc[wp][r];
  __syncthreads();
#pragma unroll
  for (int cc = 0; cc < 4; ++cc) {
    int g4 = cc * 256 + tid;
    int node = g4 >> 6, col = g4 & 63;
    float4 v = *(const float4*)&pS[node][col * 4];
    ((float4*)(y + (size_t)(n0 + node) * 256))[col] = v;
  }
}

// ---------------- SAGE-LSTM aggregation, MFMA split-bf16, 4 edge types ----------------
// gates arrive pre-scaled by log2e (cell gate 2*log2e) -> raw exp2 gate math.

__global__ __launch_bounds__(256) void lstm_mfma_kernel(const int* __restrict__ nbrAll,
    const float* __restrict__ ybase, const short* __restrict__ whh16L,
    const float* __restrict__ bihL, const float* __restrict__ bhhL, float* __restrict__ aggBase) {
  __shared__ __align__(16) unsigned pkS[2][16 * 68];
  __shared__ int nbS[16][MAXD];
  int et = blockIdx.y;
  const int* nbr = nbrAll + (size_t)et * N_NODES * MAXD;
  const float4* y4 = (const float4*)(ybase + (size_t)et * YROW);
  const short* whh16 = whh16L + (size_t)et * 32768;
  const float* bih = bihL + et * 256;
  const float* bhh = bhhL + et * 256;
  float* agg = aggBase + (size_t)et * N_NODES * HD;
  int tid = threadIdx.x, w = tid >> 6, l = tid & 63;
  int quad = l >> 4, n = l & 15, u = w * 16 + n;
  int n0 = blockIdx.x * 16;
  if (tid < 16 * MAXD) ((int*)nbS)[tid] = nbr[n0 * MAXD + tid];
  short8 Bh[4][2], Bl[4][2];
  {
    const short8* wf = (const short8*)whh16;
#pragma unroll
    for (int g = 0; g < 4; ++g)
#pragma unroll
      for (int kc = 0; kc < 2; ++kc) {
        int combo = (w * 4 + g) * 2 + kc;
        Bh[g][kc] = wf[(combo * 2 + 0) * 64 + l];
        Bl[g][kc] = wf[(combo * 2 + 1) * 64 + l];
      }
  }
  float bs[4];
#pragma unroll
  for (int g = 0; g < 4; ++g)
    bs[g] = (bih[g * 64 + u] + bhh[g * 64 + u]) * ((g == 2) ? (2.0f * LOG2E) : LOG2E);
  float c[4] = {0.f, 0.f, 0.f, 0.f}, h[4];
  short8 Ah[2], Al[2];
#pragma unroll
  for (int kc = 0; kc < 2; ++kc) { Ah[kc] = (short8)0; Al[kc] = (short8)0; }
  __syncthreads();
  float4 Y[4];
#pragma unroll
  for (int r = 0; r < 4; ++r) Y[r] = y4[(size_t)nbS[quad * 4 + r][0] * 64 + u];
  for (int t = 0; t < MAXD; ++t) {
    float yg[4][4];
#pragma unroll
    for (int r = 0; r < 4; ++r) {
      yg[0][r] = Y[r].x; yg[1][r] = Y[r].y; yg[2][r] = Y[r].z; yg[3][r] = Y[r].w;
    }
    floatx4 acc[4];
#pragma unroll
    for (int g = 0; g < 4; ++g) {
      floatx4 a = {yg[g][0], yg[g][1], yg[g][2], yg[g][3]};
      a = MFMA16(Ah[0], Bh[g][0], a);
      a = MFMA16(Ah[1], Bh[g][1], a);
      a = MFMA16(Al[0], Bh[g][0], a);
      a = MFMA16(Al[1], Bh[g][1], a);
      a = MFMA16(Ah[0], Bl[g][0], a);
      a = MFMA16(Ah[1], Bl[g][1], a);
      acc[g] = a;
    }
    if (t + 1 < MAXD) {
#pragma unroll
      for (int r = 0; r < 4; ++r) Y[r] = y4[(size_t)nbS[quad * 4 + r][t + 1] * 64 + u];
    }
    int buf = (t + 1) & 1;
#pragma unroll
    for (int r = 0; r < 4; ++r) {
      float gi = acc[0][r] + bs[0];
      float gf = acc[1][r] + bs[1];
      float gg = acc[2][r] + bs[2];
      float go = acc[3][r] + bs[3];
      float a_ = EXP2(-gi);
      float b_ = EXP2(fminf(-gg, 60.f));
      float f_ = EXP2(-gf);
      float o_ = EXP2(-go);
      float p1 = 1.f + a_, p2 = 1.f + b_, p3 = 1.f + f_;
      float d1 = p1 * p2;
      float num = fmaf(c[r], d1, (1.f - b_) * p3);
      c[r] = num * __builtin_amdgcn_rcpf(p3 * d1);
      float e_ = EXP2(c[r] * (-2.0f * LOG2E));
      h[r] = (1.f - e_) * __builtin_amdgcn_rcpf((1.f + e_) * (1.f + o_));
      unsigned ub = __float_as_uint(h[r]);
      float lo = h[r] - __uint_as_float(ub & 0xFFFF0000u);
      pkS[buf][(quad * 4 + r) * 68 + u] =
          __builtin_amdgcn_perm(ub, __float_as_uint(lo), 0x07060302u);
    }
    __syncthreads();
    if (t + 1 < MAXD) {
#pragma unroll
      for (int kc = 0; kc < 2; ++kc) {
        const unsigned* pb = &pkS[buf][n * 68 + kc * 32 + quad * 8];
        uint4 qa = *(const uint4*)pb;
        uint4 qb = *(const uint4*)(pb + 4);
        union { short8 s; unsigned d[4]; } H, L;
        H.d[0] = __builtin_amdgcn_perm(qa.y, qa.x, 0x07060302u);
        H.d[1] = __builtin_amdgcn_perm(qa.w, qa.z, 0x07060302u);
        H.d[2] = __builtin_amdgcn_perm(qb.y, qb.x, 0x07060302u);
        H.d[3] = __builtin_amdgcn_perm(qb.w, qb.z, 0x07060302u);
        L.d[0] = __builtin_amdgcn_perm(qa.y, qa.x, 0x05040100u);
        L.d[1] = __builtin_amdgcn_perm(qa.w, qa.z, 0x05040100u);
        L.d[2] = __builtin_amdgcn_perm(qb.y, qb.x, 0x05040100u);
        L.d[3] = __builtin_amdgcn_perm(qb.w, qb.z, 0x05040100u);
        Ah[kc] = H.s;
        Al[kc] = L.s;
      }
    }
  }
#pragma unroll
  for (int r = 0; r < 4; ++r)
    agg[(size_t)(n0 + quad * 4 + r) * HD + u] = h[r];
}

// ---------------- combine via MFMA ----------------

__global__ __launch_bounds__(256) void combine_mfma_kernel(const float* __restrict__ aggBase,
    const short* __restrict__ cwL, const float* __restrict__ blL,
    const float* __restrict__ xS0, const float* __restrict__ xT0, int has_res,
    float* __restrict__ outS, float* __restrict__ outT) {
  __shared__ __align__(16) float tS[3][16][68];
  int side = blockIdx.y;
  int etA = side ? 1 : 0, etB = side ? 2 : 3;
  const float* srcs[3];
  srcs[0] = aggBase + (size_t)etA * N_NODES * HD;
  srcs[1] = aggBase + (size_t)etB * N_NODES * HD;
  srcs[2] = side ? xT0 : xS0;
  float* out = side ? outT : outS;
  const short8* wf = (const short8*)cwL + (size_t)side * 3072;
  const float* blA = blL + etA * 64;
  const float* blB = blL + etB * 64;
  int tid = threadIdx.x, w = tid >> 6, l = tid & 63;
  int quad = l >> 4, n = l & 15;
  int n0 = blockIdx.x * 16;
  {
    int node = tid >> 4, f4 = tid & 15;
#pragma unroll
    for (int m = 0; m < 3; ++m) {
      float4 v = *(const float4*)(srcs[m] + (size_t)(n0 + node) * 64 + f4 * 4);
      *(float4*)&tS[m][node][f4 * 4] = v;
    }
  }
  short8 Bh[3][2], Bl[3][2];
#pragma unroll
  for (int m = 0; m < 3; ++m)
#pragma unroll
    for (int kc = 0; kc < 2; ++kc) {
      int base = (m * 8 + w * 2 + kc) * 2;
      Bh[m][kc] = wf[(base + 0) * 64 + l];
      Bl[m][kc] = wf[(base + 1) * 64 + l];
    }
  float bsum = blA[w * 16 + n] + blB[w * 16 + n];
  __syncthreads();
  floatx4 a = {0.f, 0.f, 0.f, 0.f};
#pragma unroll
  for (int m = 0; m < 3; ++m) {
    short8 Ah[2], Al[2];
    const float* hp = &tS[m][n][quad * 8];
    float4 q0 = *(const float4*)hp, q1 = *(const float4*)(hp + 4);
    float4 q2 = *(const float4*)(hp + 32), q3 = *(const float4*)(hp + 36);
    split_frag(q0, q1, Ah[0], Al[0]);
    split_frag(q2, q3, Ah[1], Al[1]);
    a = MFMA16(Ah[0], Bh[m][0], a);
    a = MFMA16(Ah[1], Bh[m][1], a);
    a = MFMA16(Al[0], Bh[m][0], a);
    a = MFMA16(Al[1], Bh[m][1], a);
    a = MFMA16(Ah[0], Bl[m][0], a);
    a = MFMA16(Ah[1], Bl[m][1], a);
  }
#pragma unroll
  for (int r = 0; r < 4; ++r) {
    int node = quad * 4 + r;
    float v = 0.5f * (a[r] + bsum);
    if (has_res) v += tS[2][node][w * 16 + n];
    out[(size_t)(n0 + node) * 64 + w * 16 + n] = fmaxf(v, 0.f);
  }
}

// ---------------- edge head via MFMA ----------------
// Block = 64 edges, 4 waves. GEMM1: [64x128]@Wg1^T (wave = 16-unit N-subtile);
// gate p via 16-lane shfl reduce + cross-wave LDS; er built on the fly into
// GEMM2 A-frags [64x80]@Wm1^T; h2 -> xS[.][0:64); GEMM3 [64x64]@Wm2^T
// (2 subtiles x 2 M-tiles per wave); h3 -> xS[.][64:96); VALU tail for Wm3.

__global__ __launch_bounds__(256) void edge_head_mfma_kernel(
    const int* __restrict__ esrc, const int* __restrict__ edst, const float* __restrict__ ea,
    const float* __restrict__ s3, const float* __restrict__ t3,
    const short* __restrict__ ehw16,
    const float* __restrict__ bg1, const float* __restrict__ Wg2,
    const float* __restrict__ bg2, const float* __restrict__ bm1,
    const float* __restrict__ bm2, const float* __restrict__ Wm3,
    const float* __restrict__ bm3, float* __restrict__ out) {
  __shared__ __align__(16) float xS[64][XST];
  __shared__ float gP[4][64];
  int tid = threadIdx.x, w = tid >> 6, l = tid & 63;
  int quad = l >> 4, n = l & 15;
  int e0 = blockIdx.x * 64;
  const short8* wf = (const short8*)ehw16;
  for (int idx = tid; idx < 2048; idx += 256) {
    int e = idx >> 5, kk = idx & 31;
    float4 v;
    if (kk < 16) v = ((const float4*)(s3 + (size_t)esrc[e0 + e] * 64))[kk];
    else         v = ((const float4*)(t3 + (size_t)edst[e0 + e] * 64))[kk - 16];
    *(float4*)&xS[e][kk * 4] = v;
  }
  {
    int e = tid >> 2, kk = tid & 3;
    *(float4*)&xS[e][128 + kk * 4] = ((const float4*)(ea + (size_t)(e0 + e) * 16))[kk];
  }
  __syncthreads();
  // ---- GEMM1: h1 = relu([se|te] @ Wg1^T + bg1); p-partials ----
  {
    short8 Bh[4], Bl[4];
#pragma unroll
    for (int kc = 0; kc < 4; ++kc) {
      int cb = w * 4 + kc;
      Bh[kc] = wf[(cb * 2 + 0) * 64 + l];
      Bl[kc] = wf[(cb * 2 + 1) * 64 + l];
    }
    float bg = bg1[w * 16 + n];
    float wg2l = Wg2[w * 16 + n];
    float red[4][4];
#pragma unroll
    for (int mt = 0; mt < 4; ++mt) {
      floatx4 a = {bg, bg, bg, bg};
#pragma unroll
      for (int kc = 0; kc < 4; ++kc) {
        const float* hp = &xS[mt * 16 + n][kc * 32 + quad * 8];
        float4 q0 = *(const float4*)hp, q1 = *(const float4*)(hp + 4);
        short8 Ah, Al;
        split_frag(q0, q1, Ah, Al);
        a = MFMA16(Ah, Bh[kc], a);
        a = MFMA16(Al, Bh[kc], a);
        a = MFMA16(Ah, Bl[kc], a);
      }
#pragma unroll
      for (int r = 0; r < 4; ++r) red[mt][r] = fmaxf(a[r], 0.f) * wg2l;
    }
#pragma unroll
    for (int mt = 0; mt < 4; ++mt)
#pragma unroll
      for (int r = 0; r < 4; ++r) {
#pragma unroll
        for (int off = 1; off < 16; off <<= 1)
          red[mt][r] += __shfl_xor(red[mt][r], off);
      }
#pragma unroll
    for (int mt = 0; mt < 4; ++mt)
#pragma unroll
      for (int r = 0; r < 4; ++r)
        if (n == mt * 4 + r) gP[w][mt * 16 + quad * 4 + r] = red[mt][r];
  }
  __syncthreads();
  // gate per A-row edge
  float gv[4];
  {
    float b2 = bg2[0];
#pragma unroll
    for (int mt = 0; mt < 4; ++mt) {
      int e = mt * 16 + n;
      float p = gP[0][e] + gP[1][e] + gP[2][e] + gP[3][e] + b2;
      gv[mt] = sigmoidf_(p);
    }
  }
  // ---- GEMM2: h2 = relu([er|ea] @ Wm1^T + bm1) ----
  floatx4 acc2[4];
  {
    short8 Bh[3], Bl[3];
#pragma unroll
    for (int kc = 0; kc < 3; ++kc) {
      int cb = 16 + w * 3 + kc;
      Bh[kc] = wf[(cb * 2 + 0) * 64 + l];
      Bl[kc] = wf[(cb * 2 + 1) * 64 + l];
    }
    float bm = bm1[w * 16 + n];
#pragma unroll
    for (int mt = 0; mt < 4; ++mt) {
      int e = mt * 16 + n;
      float g = gv[mt];
      floatx4 a = {bm, bm, bm, bm};
#pragma unroll
      for (int kc = 0; kc < 2; ++kc) {
        const float* sp = &xS[e][kc * 32 + quad * 8];
        float4 s0 = *(const float4*)sp, s1 = *(const float4*)(sp + 4);
        float4 t0 = *(const float4*)(sp + 64), t1 = *(const float4*)(sp + 68);
        float4 e0v, e1v;
        e0v.x = fmaf(g, s0.x - t0.x, t0.x); e0v.y = fmaf(g, s0.y - t0.y, t0.y);
        e0v.z = fmaf(g, s0.z - t0.z, t0.z); e0v.w = fmaf(g, s0.w - t0.w, t0.w);
        e1v.x = fmaf(g, s1.x - t1.x, t1.x); e1v.y = fmaf(g, s1.y - t1.y, t1.y);
        e1v.z = fmaf(g, s1.z - t1.z, t1.z); e1v.w = fmaf(g, s1.w - t1.w, t1.w);
        short8 Ah, Al;
        split_frag(e0v, e1v, Ah, Al);
        a = MFMA16(Ah, Bh[kc], a);
        a = MFMA16(Al, Bh[kc], a);
        a = MFMA16(Ah, Bl[kc], a);
      }
      {
        float4 z0 = {0.f, 0.f, 0.f, 0.f}, z1 = {0.f, 0.f, 0.f, 0.f};
        if (quad < 2) {
          const float* ap = &xS[e][128 + quad * 8];
          z0 = *(const float4*)ap;
          z1 = *(const float4*)(ap + 4);
        }
        short8 Ah, Al;
        split_frag(z0, z1, Ah, Al);
        a = MFMA16(Ah, Bh[2], a);
        a = MFMA16(Al, Bh[2], a);
        a = MFMA16(Ah, Bl[2], a);
      }
      acc2[mt] = a;
    }
  }
  __syncthreads();  // all er/ea reads done before overwrite
#pragma unroll
  for (int mt = 0; mt < 4; ++mt)
#pragma unroll
    for (int r = 0; r < 4; ++r)
      xS[mt * 16 + quad * 4 + r][w * 16 + n] = fmaxf(acc2[mt][r], 0.f);
  __syncthreads();
  // ---- GEMM3: h3 = relu(h2 @ Wm2^T + bm2), 32 units ----
  {
    int s = w & 1, mtb = (w >> 1) * 2;
    short8 Bh[2], Bl[2];
#pragma unroll
    for (int kc = 0; kc < 2; ++kc) {
      int cb = 28 + s * 2 + kc;
      Bh[kc] = wf[(cb * 2 + 0) * 64 + l];
      Bl[kc] = wf[(cb * 2 + 1) * 64 + l];
    }
    float bm = bm2[s * 16 + n];
#pragma unroll
    for (int mi = 0; mi < 2; ++mi) {
      int mt = mtb + mi;
      int e = mt * 16 + n;
      floatx4 a = {bm, bm, bm, bm};
#pragma unroll
      for (int kc = 0; kc < 2; ++kc) {
        const float* sp = &xS[e][kc * 32 + quad * 8];
        float4 q0 = *(const float4*)sp, q1 = *(const float4*)(sp + 4);
        short8 Ah, Al;
        split_frag(q0, q1, Ah, Al);
        a = MFMA16(Ah, Bh[kc], a);
        a = MFMA16(Al, Bh[kc], a);
        a = MFMA16(Ah, Bl[kc], a);
      }
#pragma unroll
      for (int r = 0; r < 4; ++r)
        xS[mt * 16 + quad * 4 + r][64 + s * 16 + n] = fmaxf(a[r], 0.f);
    }
  }
  __syncthreads();
  // ---- output: [64x32] @ Wm3^T + bm3 ----
  if (tid < 128) {
    int e = tid >> 1, j = tid & 1;
    const float4* hp = (const float4*)&xS[e][64];
    const float4* w3 = (const float4*)(Wm3 + j * 32);
    float a = bm3[j];
#pragma unroll
    for (int kk = 0; kk < 8; ++kk) a = fma4(w3[kk], hp[kk], a);
    out[(e0 + e) * 2 + j] = a;
  }
}

// ---------------- host orchestration ----------------

extern "C" void kernel_launch(void* const* d_in, const int* in_sizes, int n_in, void* d_out,
                              int out_size, void* d_ws, size_t ws_size, hipStream_t stream) {
  const float* x_source = (const float*)d_in[0];
  const float* x_target = (const float*)d_in[1];
  const int* edges = (const int*)d_in[2];
  const float* edge_attr = (const float*)d_in[3];
  const float* We_s1 = (const float*)d_in[4];
  const float* be_s1 = (const float*)d_in[5];
  const float* We_s2 = (const float*)d_in[6];
  const float* be_s2 = (const float*)d_in[7];
  const float* We_t1 = (const float*)d_in[8];
  const float* be_t1 = (const float*)d_in[9];
  const float* We_t2 = (const float*)d_in[10];
  const float* be_t2 = (const float*)d_in[11];
  const float* Wih = (const float*)d_in[12];
  const float* Whh = (const float*)d_in[13];
  const float* bih = (const float*)d_in[14];
  const float* bhh = (const float*)d_in[15];
  const float* Wl = (const float*)d_in[16];
  const float* bl = (const float*)d_in[17];
  const float* Wr = (const float*)d_in[18];
  const float* Wg1 = (const float*)d_in[19];
  const float* bg1 = (const float*)d_in[20];
  const float* Wg2 = (const float*)d_in[21];
  const float* bg2 = (const float*)d_in[22];
  const float* Wm1 = (const float*)d_in[23];
  const float* bm1 = (const float*)d_in[24];
  const float* Wm2 = (const float*)d_in[25];
  const float* bm2 = (const float*)d_in[26];
  const float* Wm3 = (const float*)d_in[27];
  const float* bm3 = (const float*)d_in[28];
  float* out = (float*)d_out;

  int* nbr = (int*)d_ws;                       // 4*N*12
  int* cnt = nbr + 4 * N_NODES * MAXD;         // 4*N
  int* pool = cnt + 4 * N_NODES;               // 4*N*CAP
  float* fb = (float*)(pool + 4 * N_NODES * CAP);
  float* bufS[2] = {fb, fb + N_NODES * HD};
  float* bufT[2] = {fb + 2 * N_NODES * HD, fb + 3 * N_NODES * HD};
  float* aggBase = fb + (size_t)4 * N_NODES * HD;        // 4 * N*64
  float* y4 = fb + (size_t)8 * N_NODES * HD;             // 4 * (N+1)*256
  short* whh16 = (short*)(y4 + 4 * YROW);                // 12 * 32768
  short* wih16 = whh16 + 12 * 32768;                     // 12 * 32768
  short* cw16 = wih16 + 12 * 32768;                      // 6 * 24576
  short* ehw16 = cw16 + 6 * 24576;                       // 32 * 2 * 512

  hipMemsetAsync(cnt, 0, 4 * N_NODES * sizeof(int), stream);
  prep_all_kernel<<<240, 256, 0, stream>>>(Whh, Wih, Wl, Wr, Wg1, Wm1, Wm2,
      whh16, wih16, cw16, ehw16, y4);
  scatter_kernel<<<(4 * N_EDGES + 255) / 256, 256, 0, stream>>>(edges, cnt, pool);
  sortrows_kernel<<<(4 * N_NODES + 63) / 64, 64, 0, stream>>>(cnt, pool, nbr);
  encode_both_kernel<<<dim3(N_NODES / 4, 2), 256, 0, stream>>>(x_source, x_target,
      We_s1, be_s1, We_s2, be_s2, We_t1, be_t1, We_t2, be_t2, bufS[0], bufT[0]);

  int cur = 0;
  for (int L = 0; L < 3; ++L) {
    ygemm_mfma_kernel<<<dim3(N_NODES / 16, 4), 256, 0, stream>>>(bufS[cur], bufT[cur],
        wih16 + (size_t)L * 4 * 32768, y4);
    lstm_mfma_kernel<<<dim3(N_NODES / 16, 4), 256, 0, stream>>>(nbr, y4,
        whh16 + (size_t)L * 4 * 32768, bih + L * 1024, bhh + L * 1024, aggBase);
    combine_mfma_kernel<<<dim3(N_NODES / 16, 2), 256, 0, stream>>>(aggBase,
        cw16 + (size_t)L * 2 * 24576, bl + L * 256,
        bufS[cur], bufT[cur], L > 0 ? 1 : 0, bufS[1 - cur], bufT[1 - cur]);
    cur = 1 - cur;
  }

  edge_head_mfma_kernel<<<N_EDGES / 64, 256, 0, stream>>>(edges + 4 * N_EDGES,
      edges + 5 * N_EDGES, edge_attr, bufS[cur], bufT[cur], ehw16,
      bg1, Wg2, bg2, bm1, bm2, Wm3, bm3, out);
}